// Round 11
// baseline (245.681 us; speedup 1.0000x reference)
//
#include <hip/hip_runtime.h>
#include <hip/hip_bf16.h>

namespace {

constexpr int B_ = 8, S = 2048, D = 256, H = 4, HD = 64;
constexpr int M = B_ * S;  // 16384

typedef __attribute__((ext_vector_type(8))) short bf16x8;
typedef __attribute__((ext_vector_type(4))) short bf16x4;
typedef __attribute__((ext_vector_type(4))) float f32x4;
typedef __attribute__((ext_vector_type(16))) float f32x16;
typedef __attribute__((ext_vector_type(4))) unsigned uint4v;

__device__ inline short f2bf(float x) {
  __hip_bfloat16 h = __float2bfloat16(x);
  short s;
  __builtin_memcpy(&s, &h, 2);
  return s;
}

__device__ inline f32x4 mfma16(bf16x8 a, bf16x8 b, f32x4 c) {
  return __builtin_amdgcn_mfma_f32_16x16x32_bf16(a, b, c, 0, 0, 0);
}
__device__ inline f32x16 mfma32(bf16x8 a, bf16x8 b, f32x16 c) {
  return __builtin_amdgcn_mfma_f32_32x32x16_bf16(a, b, c, 0, 0, 0);
}

// raw 2^x
__device__ inline float exp2a(float x) {
  float r;
  asm("v_exp_f32 %0, %1" : "=v"(r) : "v"(x));
  return r;
}

// HW packed f32x2 -> bf16x2 (RNE)
__device__ inline unsigned cvtpk(float lo, float hi) {
  unsigned r;
  asm("v_cvt_pk_bf16_f32 %0, %1, %2" : "=v"(r) : "v"(lo), "v"(hi));
  return r;
}

__device__ inline bf16x4 pk4(float a, float b, float c, float d) {
  unsigned lo = cvtpk(a, b), hi = cvtpk(c, d);
  uint2 u{lo, hi};
  bf16x4 r;
  __builtin_memcpy(&r, &u, 8);
  return r;
}

// load 8 fp32, convert to bf16x8
__device__ inline bf16x8 ld_cvt8(const float* p) {
  float4 a = *(const float4*)p;
  float4 b = *(const float4*)(p + 4);
  uint4v u = {cvtpk(a.x, a.y), cvtpk(a.z, a.w), cvtpk(b.x, b.y), cvtpk(b.z, b.w)};
  bf16x8 r;
  __builtin_memcpy(&r, &u, 16);
  return r;
}

// ---------------------------------------------------------------------------
// Prep: 64 blocks transpose W{q,k,v,o} fp32[k][n] -> bf16 Wt[n][k].
// ---------------------------------------------------------------------------
__global__ __launch_bounds__(256) void prep_w_kernel(
    const float* __restrict__ Wq, const float* __restrict__ Wk,
    const float* __restrict__ Wv, const float* __restrict__ Wo,
    short* __restrict__ WqT, short* __restrict__ WkT,
    short* __restrict__ WvT, short* __restrict__ WoT) {
  const int blk = blockIdx.x, t = threadIdx.x;
  const int wq = blk >> 4, n0 = (blk & 15) * 16;
  const float* W = wq == 0 ? Wq : wq == 1 ? Wk : wq == 2 ? Wv : Wo;
  short* Wt = wq == 0 ? WqT : wq == 1 ? WkT : wq == 2 ? WvT : WoT;
#pragma unroll
  for (int j4 = 0; j4 < 4; ++j4) {
    float4 v = *(const float4*)(W + (size_t)t * 256 + n0 + j4 * 4);
    Wt[(n0 + j4 * 4 + 0) * 256 + t] = f2bf(v.x);
    Wt[(n0 + j4 * 4 + 1) * 256 + t] = f2bf(v.y);
    Wt[(n0 + j4 * 4 + 2) * 256 + t] = f2bf(v.z);
    Wt[(n0 + j4 * 4 + 3) * 256 + t] = f2bf(v.w);
  }
}

// ---------------------------------------------------------------------------
// QKV GEMM: x staged fp32 -> cvt_pk -> LDS. Q scale folds 1/8*log2e;
// V written [bh][d][s] via operand swap.
// ---------------------------------------------------------------------------
__global__ __launch_bounds__(256) void gemm_qkv_kernel(
    const float* __restrict__ x,
    const short* __restrict__ WqT, const short* __restrict__ WkT,
    const short* __restrict__ WvT,
    const float* __restrict__ bq, const float* __restrict__ bk,
    const float* __restrict__ bv,
    short* __restrict__ Qo, short* __restrict__ Ko, short* __restrict__ Vt) {
  const int bx = blockIdx.x;
  const int which = blockIdx.y;
  const short* Wt = which == 0 ? WqT : which == 1 ? WkT : WvT;
  const float* bias = which == 0 ? bq : which == 1 ? bk : bv;

  __shared__ short Xs[2][64 * 32];
  __shared__ short Ws[2][256 * 32];

  const int tid = threadIdx.x;
  const int wid = tid >> 6, lane = tid & 63;
  const int l15 = lane & 15, l4 = lane >> 4;
  const int nt0 = wid * 4;

  const float* xsrc = x + ((size_t)(bx * 64 + (tid >> 2))) * 256 + (tid & 3) * 8;
  const short* wsrc = Wt + ((size_t)(tid >> 2)) * 256 + (tid & 3) * 8;
  short* xdst0 = &Xs[0][tid * 8];
  short* xdst1 = &Xs[1][tid * 8];
  short* wdst0 = &Ws[0][tid * 8];
  short* wdst1 = &Ws[1][tid * 8];

  bf16x8 xr, wr[4];
  xr = ld_cvt8(xsrc);
#pragma unroll
  for (int p = 0; p < 4; ++p) wr[p] = *(const bf16x8*)(wsrc + (size_t)p * 64 * 256);
  *(bf16x8*)xdst0 = xr;
#pragma unroll
  for (int p = 0; p < 4; ++p) *(bf16x8*)(wdst0 + p * 2048) = wr[p];
  __syncthreads();

  f32x4 acc[4][4];
#pragma unroll
  for (int i = 0; i < 4; ++i)
#pragma unroll
    for (int mh = 0; mh < 4; ++mh) acc[i][mh] = f32x4{0.f, 0.f, 0.f, 0.f};

  for (int ks = 0; ks < 8; ++ks) {
    const int cur = ks & 1;
    if (ks < 7) {
      xr = ld_cvt8(xsrc + (ks + 1) * 32);
#pragma unroll
      for (int p = 0; p < 4; ++p)
        wr[p] = *(const bf16x8*)(wsrc + (size_t)p * 64 * 256 + (ks + 1) * 32);
    }
    bf16x8 wf[4], xf[4];
#pragma unroll
    for (int i = 0; i < 4; ++i)
      wf[i] = *(const bf16x8*)&Ws[cur][((nt0 + i) * 16 + l15) * 32 + l4 * 8];
#pragma unroll
    for (int mh = 0; mh < 4; ++mh)
      xf[mh] = *(const bf16x8*)&Xs[cur][(mh * 16 + l15) * 32 + l4 * 8];
    if (which == 2) {
#pragma unroll
      for (int i = 0; i < 4; ++i)
#pragma unroll
        for (int mh = 0; mh < 4; ++mh)
          acc[i][mh] = mfma16(xf[mh], wf[i], acc[i][mh]);  // D[m][n]
    } else {
#pragma unroll
      for (int i = 0; i < 4; ++i)
#pragma unroll
        for (int mh = 0; mh < 4; ++mh)
          acc[i][mh] = mfma16(wf[i], xf[mh], acc[i][mh]);  // D[n][m]
    }
    if (ks < 7) {
      short* xd = (cur ? xdst0 : xdst1);
      short* wd = (cur ? wdst0 : wdst1);
      *(bf16x8*)xd = xr;
#pragma unroll
      for (int p = 0; p < 4; ++p) *(bf16x8*)(wd + p * 2048) = wr[p];
    }
    __syncthreads();
  }

  if (which == 2) {
    const int m0 = bx * 64 + l4 * 4;
#pragma unroll
    for (int i = 0; i < 4; ++i) {
      const int n = (nt0 + i) * 16 + l15;
      const float bi = bias[n];
      const int h = n >> 6, d = n & 63;
#pragma unroll
      for (int mh = 0; mh < 4; ++mh) {
        const int m = m0 + mh * 16;
        const int bb = m >> 11, s0 = m & 2047;
        bf16x4 r = pk4(acc[i][mh][0] + bi, acc[i][mh][1] + bi,
                       acc[i][mh][2] + bi, acc[i][mh][3] + bi);
        *(bf16x4*)(Vt + (((size_t)bb * H + h) * HD + d) * S + s0) = r;
      }
    }
  } else {
    const float scale = which == 0 ? 0.18033688011112042f : 1.0f;  // 1/8*log2e
    short* outp = which == 0 ? Qo : Ko;
#pragma unroll
    for (int i = 0; i < 4; ++i) {
      const int n0 = (nt0 + i) * 16 + l4 * 4;
      float4 bi = *(const float4*)(bias + n0);
      const int h = n0 >> 6, d0 = n0 & 63;
#pragma unroll
      for (int mh = 0; mh < 4; ++mh) {
        const int m = bx * 64 + mh * 16 + l15;
        const int bb = m >> 11, s = m & 2047;
        bf16x4 r = pk4((acc[i][mh][0] + bi.x) * scale, (acc[i][mh][1] + bi.y) * scale,
                       (acc[i][mh][2] + bi.z) * scale, (acc[i][mh][3] + bi.w) * scale);
        *(bf16x4*)(outp + (((size_t)bb * H + h) * S + s) * HD + d0) = r;
      }
    }
  }
}

// ---------------------------------------------------------------------------
// Split-KV merge: Abf[m][256] = round_bf16((O0+O1) / (l0+l1)).
// Opart layout [sp][bh][q][64] fp32; lpart [sp][bh][2048] fp32.
// ---------------------------------------------------------------------------
__global__ __launch_bounds__(256) void merge_kernel(
    const float* __restrict__ O0, const float* __restrict__ O1,
    const float* __restrict__ l0, const float* __restrict__ l1,
    short* __restrict__ Abf) {
  const size_t g = ((size_t)blockIdx.x * 256 + threadIdx.x) * 8;  // over 32*2048*64
  const int bh = (int)(g >> 17);
  const int rem = (int)(g & 131071);
  const int q = rem >> 6, d = rem & 63;
  const float iv = 1.0f / (l0[(size_t)bh * 2048 + q] + l1[(size_t)bh * 2048 + q]);
  float4 a0 = *(const float4*)(O0 + g);
  float4 a1 = *(const float4*)(O0 + g + 4);
  float4 b0 = *(const float4*)(O1 + g);
  float4 b1 = *(const float4*)(O1 + g + 4);
  uint4v u = {cvtpk((a0.x + b0.x) * iv, (a0.y + b0.y) * iv),
              cvtpk((a0.z + b0.z) * iv, (a0.w + b0.w) * iv),
              cvtpk((a1.x + b1.x) * iv, (a1.y + b1.y) * iv),
              cvtpk((a1.z + b1.z) * iv, (a1.w + b1.w) * iv)};
  bf16x8 r;
  __builtin_memcpy(&r, &u, 16);
  const int b = bh >> 2, h = bh & 3;
  *(bf16x8*)(Abf + ((size_t)b * 2048 + q) * 256 + h * 64 + d) = r;
}

// ---------------------------------------------------------------------------
// Out projection GEMM (R8 version: bf16 A in, fp32 out)
// ---------------------------------------------------------------------------
__global__ __launch_bounds__(256) void gemm_out_kernel(
    const short* __restrict__ Abf, const short* __restrict__ WoT,
    const float* __restrict__ bo, float* __restrict__ out) {
  const int bx = blockIdx.x;
  __shared__ short Xs[2][64 * 32];
  __shared__ short Ws[2][256 * 32];

  const int tid = threadIdx.x;
  const int wid = tid >> 6, lane = tid & 63;
  const int l15 = lane & 15, l4 = lane >> 4;
  const int nt0 = wid * 4;

  const short* xsrc = Abf + ((size_t)(bx * 64 + (tid >> 2))) * 256 + (tid & 3) * 8;
  const short* wsrc = WoT + ((size_t)(tid >> 2)) * 256 + (tid & 3) * 8;
  short* xdst0 = &Xs[0][tid * 8];
  short* xdst1 = &Xs[1][tid * 8];
  short* wdst0 = &Ws[0][tid * 8];
  short* wdst1 = &Ws[1][tid * 8];

  bf16x8 xr, wr[4];
  xr = *(const bf16x8*)xsrc;
#pragma unroll
  for (int p = 0; p < 4; ++p) wr[p] = *(const bf16x8*)(wsrc + (size_t)p * 64 * 256);
  *(bf16x8*)xdst0 = xr;
#pragma unroll
  for (int p = 0; p < 4; ++p) *(bf16x8*)(wdst0 + p * 2048) = wr[p];
  __syncthreads();

  f32x4 acc[4][4];
#pragma unroll
  for (int i = 0; i < 4; ++i)
#pragma unroll
    for (int mh = 0; mh < 4; ++mh) acc[i][mh] = f32x4{0.f, 0.f, 0.f, 0.f};

  for (int ks = 0; ks < 8; ++ks) {
    const int cur = ks & 1;
    if (ks < 7) {
      xr = *(const bf16x8*)(xsrc + (ks + 1) * 32);
#pragma unroll
      for (int p = 0; p < 4; ++p)
        wr[p] = *(const bf16x8*)(wsrc + (size_t)p * 64 * 256 + (ks + 1) * 32);
    }
    bf16x8 wf[4], xf[4];
#pragma unroll
    for (int i = 0; i < 4; ++i)
      wf[i] = *(const bf16x8*)&Ws[cur][((nt0 + i) * 16 + l15) * 32 + l4 * 8];
#pragma unroll
    for (int mh = 0; mh < 4; ++mh)
      xf[mh] = *(const bf16x8*)&Xs[cur][(mh * 16 + l15) * 32 + l4 * 8];
#pragma unroll
    for (int i = 0; i < 4; ++i)
#pragma unroll
      for (int mh = 0; mh < 4; ++mh)
        acc[i][mh] = mfma16(wf[i], xf[mh], acc[i][mh]);
    if (ks < 7) {
      short* xd = (cur ? xdst0 : xdst1);
      short* wd = (cur ? wdst0 : wdst1);
      *(bf16x8*)xd = xr;
#pragma unroll
      for (int p = 0; p < 4; ++p) *(bf16x8*)(wd + p * 2048) = wr[p];
    }
    __syncthreads();
  }

#pragma unroll
  for (int i = 0; i < 4; ++i) {
    const int n0 = (nt0 + i) * 16 + l4 * 4;
    float4 bi = *(const float4*)(bo + n0);
#pragma unroll
    for (int mh = 0; mh < 4; ++mh) {
      const int m = bx * 64 + mh * 16 + l15;
      float4 r;
      r.x = acc[i][mh][0] + bi.x;
      r.y = acc[i][mh][1] + bi.y;
      r.z = acc[i][mh][2] + bi.z;
      r.w = acc[i][mh][3] + bi.w;
      *(float4*)(out + (size_t)m * 256 + n0) = r;
    }
  }
}

// ---------------------------------------------------------------------------
// Flash attention v11: split-KV x2 via blockIdx.y (additive partials, fp32
// partial O + l), R8's PROVEN double-buffered schedule (both K,V staged per
// tile, 2 barriers), PACKED LDS tiles: logical [64][64] stored [32][128]
// (row r -> phys row r&31, col |= (r>>5)*64, then ^(r&15)*8 swizzle).
// 4 buffers x 8KB = 32KB -> 4 blocks/CU.
// ---------------------------------------------------------------------------
__global__ __launch_bounds__(256, 4) void attn_kernel11(
    const short* __restrict__ Q, const short* __restrict__ K,
    const short* __restrict__ VT, float* __restrict__ Opart,
    float* __restrict__ lpart) {
  const int lin = blockIdx.x;        // 512
  const int bh = lin & 31;           // same-bh blocks land on same XCD
  const int qt = lin >> 5;           // 0..15
  const int sp = blockIdx.y;         // split 0/1
  const int tid = threadIdx.x, wid = tid >> 6, lane = tid & 63;
  const int q31 = lane & 31, h = lane >> 5;
  constexpr int NT = 16;  // KV tiles per split

  __shared__ short Ks[2][32 * 128];  // packed [64][64] tiles
  __shared__ short Vs[2][32 * 128];

  const short* Kgs = K + (size_t)bh * S * HD + (size_t)sp * 1024 * HD;
  const short* Vg = VT + (size_t)bh * HD * S;
  const int vcol0 = sp * 1024;
  const int qrow = qt * 128 + wid * 32;

  const short* Qg = Q + ((size_t)bh * S + qrow + q31) * HD + h * 8;
  bf16x8 qf[4];
#pragma unroll
  for (int ds = 0; ds < 4; ++ds) qf[ds] = *(const bf16x8*)(Qg + ds * 16);

  bf16x8 ones;
#pragma unroll
  for (int i = 0; i < 8; ++i) ones[i] = (short)0x3F80;

  // staging addresses (packed): logical row srow 0..63
  const int srow = tid >> 2;
  const int pr = srow & 31;
  const int scol = (tid & 3) * 16;
  const int cb0 = ((srow >> 5) << 6) + scol;  // half-select bit 6
  const int swz = (pr & 15) * 8;
  const int c0 = cb0 ^ swz;
  const int c1 = (cb0 + 8) ^ swz;
  const int sbase = pr * 128;

  // fragment read cols: logical rows q31 (half0) / 32+q31 (half1), same phys row
  const int fs = (q31 & 15) * 8;
  int colA[4], colB[4];
#pragma unroll
  for (int ds = 0; ds < 4; ++ds) {
    colA[ds] = (ds * 16 + h * 8) ^ fs;
    colB[ds] = (64 + ds * 16 + h * 8) ^ fs;
  }
  const int rbase = q31 * 128;

  // ---- prologue: stage K(0),V(0) -> buf0; load K(1),V(1) ----
  bf16x8 kr0, kr1, vr0, vr1;
  kr0 = *(const bf16x8*)(Kgs + (size_t)srow * HD + scol);
  kr1 = *(const bf16x8*)(Kgs + (size_t)srow * HD + scol + 8);
  vr0 = *(const bf16x8*)(Vg + (size_t)srow * S + vcol0 + scol);
  vr1 = *(const bf16x8*)(Vg + (size_t)srow * S + vcol0 + scol + 8);
  *(bf16x8*)&Ks[0][sbase + c0] = kr0;
  *(bf16x8*)&Ks[0][sbase + c1] = kr1;
  *(bf16x8*)&Vs[0][sbase + c0] = vr0;
  *(bf16x8*)&Vs[0][sbase + c1] = vr1;
  {
    const short* Kn = Kgs + (size_t)64 * HD;
    kr0 = *(const bf16x8*)(Kn + (size_t)srow * HD + scol);
    kr1 = *(const bf16x8*)(Kn + (size_t)srow * HD + scol + 8);
    vr0 = *(const bf16x8*)(Vg + (size_t)srow * S + vcol0 + 64 + scol);
    vr1 = *(const bf16x8*)(Vg + (size_t)srow * S + vcol0 + 64 + scol + 8);
  }
  __syncthreads();

  f32x16 o0, o1, lsum;
#pragma unroll
  for (int i = 0; i < 16; ++i) { o0[i] = 0.f; o1[i] = 0.f; lsum[i] = 0.f; }
  bf16x8 pB[4];

#define EXPPACK(S0, S1)                                               \
  {                                                                   \
    _Pragma("unroll") for (int win = 0; win < 2; ++win) {             \
      const f32x16& sc = win ? (S1) : (S0);                           \
      float p[16];                                                    \
      _Pragma("unroll") for (int r = 0; r < 16; ++r)                  \
          p[r] = exp2a(sc[r]);                                        \
      unsigned w[8];                                                  \
      _Pragma("unroll") for (int i = 0; i < 8; ++i)                   \
          w[i] = cvtpk(p[2 * i], p[2 * i + 1]);                       \
      unsigned x0 = w[0], y0 = w[2], x1 = w[1], y1 = w[3];            \
      unsigned x2 = w[4], y2 = w[6], x3 = w[5], y3 = w[7];            \
      asm("v_permlane32_swap_b32 %0, %1" : "+v"(x0), "+v"(y0));       \
      asm("v_permlane32_swap_b32 %0, %1" : "+v"(x1), "+v"(y1));       \
      asm("v_permlane32_swap_b32 %0, %1" : "+v"(x2), "+v"(y2));       \
      asm("v_permlane32_swap_b32 %0, %1" : "+v"(x3), "+v"(y3));       \
      uint4v u0 = {x0, x1, y0, y1};                                   \
      uint4v u1 = {x2, x3, y2, y3};                                   \
      __builtin_memcpy(&pB[win * 2 + 0], &u0, 16);                    \
      __builtin_memcpy(&pB[win * 2 + 1], &u1, 16);                    \
    }                                                                 \
  }

  // ---- peeled iteration 0: QK(0); exp(0); B1; write K(1),V(1)->buf1; B2 ----
  {
    f32x16 sc0, sc1;
#pragma unroll
    for (int i = 0; i < 16; ++i) { sc0[i] = 0.f; sc1[i] = 0.f; }
    __builtin_amdgcn_s_setprio(1);
#pragma unroll
    for (int ds = 0; ds < 4; ++ds) {
      bf16x8 k0 = *(const bf16x8*)&Ks[0][rbase + colA[ds]];
      bf16x8 k1 = *(const bf16x8*)&Ks[0][rbase + colB[ds]];
      sc0 = mfma32(k0, qf[ds], sc0);
      sc1 = mfma32(k1, qf[ds], sc1);
    }
    __builtin_amdgcn_s_setprio(0);
    EXPPACK(sc0, sc1);
    __syncthreads();
    *(bf16x8*)&Ks[1][sbase + c0] = kr0;
    *(bf16x8*)&Ks[1][sbase + c1] = kr1;
    *(bf16x8*)&Vs[1][sbase + c0] = vr0;
    *(bf16x8*)&Vs[1][sbase + c1] = vr1;
    __syncthreads();
  }

  // ---- main loop t = 1 .. NT-1 (R8 invariants: Ks[cur]=K(t), Vs[prv]=V(t-1)) ----
  for (int kt = 1; kt < NT; ++kt) {
    const int cur = kt & 1, prv = cur ^ 1;
    if (kt + 1 < NT) {
      const short* Kn = Kgs + (size_t)(kt + 1) * 64 * HD;
      kr0 = *(const bf16x8*)(Kn + (size_t)srow * HD + scol);
      kr1 = *(const bf16x8*)(Kn + (size_t)srow * HD + scol + 8);
      vr0 = *(const bf16x8*)(Vg + (size_t)srow * S + vcol0 + (kt + 1) * 64 + scol);
      vr1 = *(const bf16x8*)(Vg + (size_t)srow * S + vcol0 + (kt + 1) * 64 + scol + 8);
    }

    f32x16 sc0, sc1;
#pragma unroll
    for (int i = 0; i < 16; ++i) { sc0[i] = 0.f; sc1[i] = 0.f; }

    __builtin_amdgcn_s_setprio(1);
#pragma unroll
    for (int ds = 0; ds < 4; ++ds) {
      bf16x8 k0 = *(const bf16x8*)&Ks[cur][rbase + colA[ds]];
      bf16x8 k1 = *(const bf16x8*)&Ks[cur][rbase + colB[ds]];
      sc0 = mfma32(k0, qf[ds], sc0);
      sc1 = mfma32(k1, qf[ds], sc1);
      bf16x8 v0 = *(const bf16x8*)&Vs[prv][rbase + colA[ds]];
      bf16x8 v1 = *(const bf16x8*)&Vs[prv][rbase + colB[ds]];
      o0 = mfma32(v0, pB[ds], o0);
      o1 = mfma32(v1, pB[ds], o1);
      lsum = mfma32(ones, pB[ds], lsum);
    }
    __builtin_amdgcn_s_setprio(0);

    EXPPACK(sc0, sc1);
    __syncthreads();  // B1: reads of buf[prv]/buf[cur] done
    if (kt + 1 < NT) {
      *(bf16x8*)&Ks[prv][sbase + c0] = kr0;
      *(bf16x8*)&Ks[prv][sbase + c1] = kr1;
      *(bf16x8*)&Vs[prv][sbase + c0] = vr0;
      *(bf16x8*)&Vs[prv][sbase + c1] = vr1;
    }
    __syncthreads();  // B2: writes visible
  }

  // ---- epilogue: PV(NT-1) from Vs[(NT-1)&1]; pB = P(NT-1) ----
  {
    const int cur = (NT - 1) & 1;
    __builtin_amdgcn_s_setprio(1);
#pragma unroll
    for (int ds = 0; ds < 4; ++ds) {
      bf16x8 v0 = *(const bf16x8*)&Vs[cur][rbase + colA[ds]];
      bf16x8 v1 = *(const bf16x8*)&Vs[cur][rbase + colB[ds]];
      o0 = mfma32(v0, pB[ds], o0);
      o1 = mfma32(v1, pB[ds], o1);
      lsum = mfma32(ones, pB[ds], lsum);
    }
    __builtin_amdgcn_s_setprio(0);
  }
#undef EXPPACK

  // ---- write fp32 partial O + l: layout [sp][bh][q][64] ----
  float* op = Opart + (((size_t)sp * 32 + bh) * 2048 + qrow + q31) * 64;
#pragma unroll
  for (int dt = 0; dt < 2; ++dt) {
    const f32x16& o = dt ? o1 : o0;
#pragma unroll
    for (int g = 0; g < 4; ++g) {
      const int d0 = dt * 32 + 8 * g + 4 * h;
      float4 r;
      r.x = o[4 * g + 0];
      r.y = o[4 * g + 1];
      r.z = o[4 * g + 2];
      r.w = o[4 * g + 3];
      *(float4*)(op + d0) = r;
    }
  }
  if (lane < 32) {
    lpart[((size_t)sp * 32 + bh) * 2048 + qrow + q31] = lsum[0];
  }
}

}  // namespace

extern "C" void kernel_launch(void* const* d_in, const int* in_sizes, int n_in,
                              void* d_out, int out_size, void* d_ws, size_t ws_size,
                              hipStream_t stream) {
  const float* x  = (const float*)d_in[0];
  const float* Wq = (const float*)d_in[1];
  const float* bq = (const float*)d_in[2];
  const float* Wk = (const float*)d_in[3];
  const float* bk = (const float*)d_in[4];
  const float* Wv = (const float*)d_in[5];
  const float* bv = (const float*)d_in[6];
  const float* Wo = (const float*)d_in[7];
  const float* bo = (const float*)d_in[8];
  float* out = (float*)d_out;

  const size_t per = (size_t)M * D;  // 4,194,304 elems
  short* WqT = (short*)d_ws;
  short* WkT = WqT + 256 * 256;
  short* WvT = WkT + 256 * 256;
  short* WoT = WvT + 256 * 256;
  short* Qbf = WoT + 256 * 256;
  short* Kbf = Qbf + per;
  short* Vt  = Kbf + per;            // [bh][d][s] bf16
  float* Op0 = (float*)(Vt + per);   // partial O split 0 (fp32)
  float* Op1 = Op0 + per;            // partial O split 1 (fp32)
  float* lp  = Op1 + per;            // l partials [2][32][2048] f32
  float* lp0 = lp;
  float* lp1 = lp + 32 * 2048;
  short* Abf = Qbf;                  // alias: Q dead after attn

  prep_w_kernel<<<64, 256, 0, stream>>>(Wq, Wk, Wv, Wo, WqT, WkT, WvT, WoT);
  gemm_qkv_kernel<<<dim3(256, 3), 256, 0, stream>>>(x, WqT, WkT, WvT, bq, bk, bv,
                                                    Qbf, Kbf, Vt);
  attn_kernel11<<<dim3(512, 2), 256, 0, stream>>>(Qbf, Kbf, Vt, Op0, lp);
  merge_kernel<<<2048, 256, 0, stream>>>(Op0, Op1, lp0, lp1, Abf);
  gemm_out_kernel<<<256, 256, 0, stream>>>(Abf, WoT, bo, out);
}

// Round 12
// 126.835 us; speedup vs baseline: 1.9370x; 1.9370x over previous
//
#include <hip/hip_runtime.h>
#include <hip/hip_bf16.h>

namespace {

constexpr int B_ = 8, S = 2048, D = 256, H = 4, HD = 64;
constexpr int M = B_ * S;  // 16384

typedef __attribute__((ext_vector_type(8))) short bf16x8;
typedef __attribute__((ext_vector_type(4))) short bf16x4;
typedef __attribute__((ext_vector_type(4))) float f32x4;
typedef __attribute__((ext_vector_type(16))) float f32x16;
typedef __attribute__((ext_vector_type(4))) unsigned uint4v;

__device__ inline short f2bf(float x) {
  __hip_bfloat16 h = __float2bfloat16(x);
  short s;
  __builtin_memcpy(&s, &h, 2);
  return s;
}

__device__ inline f32x4 mfma16(bf16x8 a, bf16x8 b, f32x4 c) {
  return __builtin_amdgcn_mfma_f32_16x16x32_bf16(a, b, c, 0, 0, 0);
}
__device__ inline f32x16 mfma32(bf16x8 a, bf16x8 b, f32x16 c) {
  return __builtin_amdgcn_mfma_f32_32x32x16_bf16(a, b, c, 0, 0, 0);
}

// raw 2^x
__device__ inline float exp2a(float x) {
  float r;
  asm("v_exp_f32 %0, %1" : "=v"(r) : "v"(x));
  return r;
}

// HW packed f32x2 -> bf16x2 (RNE)
__device__ inline unsigned cvtpk(float lo, float hi) {
  unsigned r;
  asm("v_cvt_pk_bf16_f32 %0, %1, %2" : "=v"(r) : "v"(lo), "v"(hi));
  return r;
}

__device__ inline bf16x4 pk4(float a, float b, float c, float d) {
  unsigned lo = cvtpk(a, b), hi = cvtpk(c, d);
  uint2 u{lo, hi};
  bf16x4 r;
  __builtin_memcpy(&r, &u, 8);
  return r;
}

// load 8 fp32, convert to bf16x8
__device__ inline bf16x8 ld_cvt8(const float* p) {
  float4 a = *(const float4*)p;
  float4 b = *(const float4*)(p + 4);
  uint4v u = {cvtpk(a.x, a.y), cvtpk(a.z, a.w), cvtpk(b.x, b.y), cvtpk(b.z, b.w)};
  bf16x8 r;
  __builtin_memcpy(&r, &u, 16);
  return r;
}

// ---------------------------------------------------------------------------
// Prep: 64 blocks transpose W{q,k,v,o} fp32[k][n] -> bf16 Wt[n][k].
// ---------------------------------------------------------------------------
__global__ __launch_bounds__(256) void prep_w_kernel(
    const float* __restrict__ Wq, const float* __restrict__ Wk,
    const float* __restrict__ Wv, const float* __restrict__ Wo,
    short* __restrict__ WqT, short* __restrict__ WkT,
    short* __restrict__ WvT, short* __restrict__ WoT) {
  const int blk = blockIdx.x, t = threadIdx.x;
  const int wq = blk >> 4, n0 = (blk & 15) * 16;
  const float* W = wq == 0 ? Wq : wq == 1 ? Wk : wq == 2 ? Wv : Wo;
  short* Wt = wq == 0 ? WqT : wq == 1 ? WkT : wq == 2 ? WvT : WoT;
#pragma unroll
  for (int j4 = 0; j4 < 4; ++j4) {
    float4 v = *(const float4*)(W + (size_t)t * 256 + n0 + j4 * 4);
    Wt[(n0 + j4 * 4 + 0) * 256 + t] = f2bf(v.x);
    Wt[(n0 + j4 * 4 + 1) * 256 + t] = f2bf(v.y);
    Wt[(n0 + j4 * 4 + 2) * 256 + t] = f2bf(v.z);
    Wt[(n0 + j4 * 4 + 3) * 256 + t] = f2bf(v.w);
  }
}

// ---------------------------------------------------------------------------
// QKV GEMM: x staged fp32 -> cvt_pk -> LDS. Q scale folds 1/8*log2e;
// V written [bh][d][s] via operand swap.
// ---------------------------------------------------------------------------
__global__ __launch_bounds__(256) void gemm_qkv_kernel(
    const float* __restrict__ x,
    const short* __restrict__ WqT, const short* __restrict__ WkT,
    const short* __restrict__ WvT,
    const float* __restrict__ bq, const float* __restrict__ bk,
    const float* __restrict__ bv,
    short* __restrict__ Qo, short* __restrict__ Ko, short* __restrict__ Vt) {
  const int bx = blockIdx.x;
  const int which = blockIdx.y;
  const short* Wt = which == 0 ? WqT : which == 1 ? WkT : WvT;
  const float* bias = which == 0 ? bq : which == 1 ? bk : bv;

  __shared__ short Xs[2][64 * 32];
  __shared__ short Ws[2][256 * 32];

  const int tid = threadIdx.x;
  const int wid = tid >> 6, lane = tid & 63;
  const int l15 = lane & 15, l4 = lane >> 4;
  const int nt0 = wid * 4;

  const float* xsrc = x + ((size_t)(bx * 64 + (tid >> 2))) * 256 + (tid & 3) * 8;
  const short* wsrc = Wt + ((size_t)(tid >> 2)) * 256 + (tid & 3) * 8;
  short* xdst0 = &Xs[0][tid * 8];
  short* xdst1 = &Xs[1][tid * 8];
  short* wdst0 = &Ws[0][tid * 8];
  short* wdst1 = &Ws[1][tid * 8];

  bf16x8 xr, wr[4];
  xr = ld_cvt8(xsrc);
#pragma unroll
  for (int p = 0; p < 4; ++p) wr[p] = *(const bf16x8*)(wsrc + (size_t)p * 64 * 256);
  *(bf16x8*)xdst0 = xr;
#pragma unroll
  for (int p = 0; p < 4; ++p) *(bf16x8*)(wdst0 + p * 2048) = wr[p];
  __syncthreads();

  f32x4 acc[4][4];
#pragma unroll
  for (int i = 0; i < 4; ++i)
#pragma unroll
    for (int mh = 0; mh < 4; ++mh) acc[i][mh] = f32x4{0.f, 0.f, 0.f, 0.f};

  for (int ks = 0; ks < 8; ++ks) {
    const int cur = ks & 1;
    if (ks < 7) {
      xr = ld_cvt8(xsrc + (ks + 1) * 32);
#pragma unroll
      for (int p = 0; p < 4; ++p)
        wr[p] = *(const bf16x8*)(wsrc + (size_t)p * 64 * 256 + (ks + 1) * 32);
    }
    bf16x8 wf[4], xf[4];
#pragma unroll
    for (int i = 0; i < 4; ++i)
      wf[i] = *(const bf16x8*)&Ws[cur][((nt0 + i) * 16 + l15) * 32 + l4 * 8];
#pragma unroll
    for (int mh = 0; mh < 4; ++mh)
      xf[mh] = *(const bf16x8*)&Xs[cur][(mh * 16 + l15) * 32 + l4 * 8];
    if (which == 2) {
#pragma unroll
      for (int i = 0; i < 4; ++i)
#pragma unroll
        for (int mh = 0; mh < 4; ++mh)
          acc[i][mh] = mfma16(xf[mh], wf[i], acc[i][mh]);  // D[m][n]
    } else {
#pragma unroll
      for (int i = 0; i < 4; ++i)
#pragma unroll
        for (int mh = 0; mh < 4; ++mh)
          acc[i][mh] = mfma16(wf[i], xf[mh], acc[i][mh]);  // D[n][m]
    }
    if (ks < 7) {
      short* xd = (cur ? xdst0 : xdst1);
      short* wd = (cur ? wdst0 : wdst1);
      *(bf16x8*)xd = xr;
#pragma unroll
      for (int p = 0; p < 4; ++p) *(bf16x8*)(wd + p * 2048) = wr[p];
    }
    __syncthreads();
  }

  if (which == 2) {
    const int m0 = bx * 64 + l4 * 4;
#pragma unroll
    for (int i = 0; i < 4; ++i) {
      const int n = (nt0 + i) * 16 + l15;
      const float bi = bias[n];
      const int h = n >> 6, d = n & 63;
#pragma unroll
      for (int mh = 0; mh < 4; ++mh) {
        const int m = m0 + mh * 16;
        const int bb = m >> 11, s0 = m & 2047;
        bf16x4 r = pk4(acc[i][mh][0] + bi, acc[i][mh][1] + bi,
                       acc[i][mh][2] + bi, acc[i][mh][3] + bi);
        *(bf16x4*)(Vt + (((size_t)bb * H + h) * HD + d) * S + s0) = r;
      }
    }
  } else {
    const float scale = which == 0 ? 0.18033688011112042f : 1.0f;  // 1/8*log2e
    short* outp = which == 0 ? Qo : Ko;
#pragma unroll
    for (int i = 0; i < 4; ++i) {
      const int n0 = (nt0 + i) * 16 + l4 * 4;
      float4 bi = *(const float4*)(bias + n0);
      const int h = n0 >> 6, d0 = n0 & 63;
#pragma unroll
      for (int mh = 0; mh < 4; ++mh) {
        const int m = bx * 64 + mh * 16 + l15;
        const int bb = m >> 11, s = m & 2047;
        bf16x4 r = pk4((acc[i][mh][0] + bi.x) * scale, (acc[i][mh][1] + bi.y) * scale,
                       (acc[i][mh][2] + bi.z) * scale, (acc[i][mh][3] + bi.w) * scale);
        *(bf16x4*)(outp + (((size_t)bb * H + h) * S + s) * HD + d0) = r;
      }
    }
  }
}

// ---------------------------------------------------------------------------
// Split-KV merge: Abf[m][256] = round_bf16((O0+O1) / (l0+l1)).
// Opart layout [sp][bh][q][64] fp32; lpart [sp][bh][2048] fp32.
// ---------------------------------------------------------------------------
__global__ __launch_bounds__(256) void merge_kernel(
    const float* __restrict__ O0, const float* __restrict__ O1,
    const float* __restrict__ l0, const float* __restrict__ l1,
    short* __restrict__ Abf) {
  const size_t g = ((size_t)blockIdx.x * 256 + threadIdx.x) * 8;  // over 32*2048*64
  const int bh = (int)(g >> 17);
  const int rem = (int)(g & 131071);
  const int q = rem >> 6, d = rem & 63;
  const float iv = 1.0f / (l0[(size_t)bh * 2048 + q] + l1[(size_t)bh * 2048 + q]);
  float4 a0 = *(const float4*)(O0 + g);
  float4 a1 = *(const float4*)(O0 + g + 4);
  float4 b0 = *(const float4*)(O1 + g);
  float4 b1 = *(const float4*)(O1 + g + 4);
  uint4v u = {cvtpk((a0.x + b0.x) * iv, (a0.y + b0.y) * iv),
              cvtpk((a0.z + b0.z) * iv, (a0.w + b0.w) * iv),
              cvtpk((a1.x + b1.x) * iv, (a1.y + b1.y) * iv),
              cvtpk((a1.z + b1.z) * iv, (a1.w + b1.w) * iv)};
  bf16x8 r;
  __builtin_memcpy(&r, &u, 16);
  const int b = bh >> 2, h = bh & 3;
  *(bf16x8*)(Abf + ((size_t)b * 2048 + q) * 256 + h * 64 + d) = r;
}

// ---------------------------------------------------------------------------
// Out projection GEMM (bf16 A in, fp32 out)
// ---------------------------------------------------------------------------
__global__ __launch_bounds__(256) void gemm_out_kernel(
    const short* __restrict__ Abf, const short* __restrict__ WoT,
    const float* __restrict__ bo, float* __restrict__ out) {
  const int bx = blockIdx.x;
  __shared__ short Xs[2][64 * 32];
  __shared__ short Ws[2][256 * 32];

  const int tid = threadIdx.x;
  const int wid = tid >> 6, lane = tid & 63;
  const int l15 = lane & 15, l4 = lane >> 4;
  const int nt0 = wid * 4;

  const short* xsrc = Abf + ((size_t)(bx * 64 + (tid >> 2))) * 256 + (tid & 3) * 8;
  const short* wsrc = WoT + ((size_t)(tid >> 2)) * 256 + (tid & 3) * 8;
  short* xdst0 = &Xs[0][tid * 8];
  short* xdst1 = &Xs[1][tid * 8];
  short* wdst0 = &Ws[0][tid * 8];
  short* wdst1 = &Ws[1][tid * 8];

  bf16x8 xr, wr[4];
  xr = *(const bf16x8*)xsrc;
#pragma unroll
  for (int p = 0; p < 4; ++p) wr[p] = *(const bf16x8*)(wsrc + (size_t)p * 64 * 256);
  *(bf16x8*)xdst0 = xr;
#pragma unroll
  for (int p = 0; p < 4; ++p) *(bf16x8*)(wdst0 + p * 2048) = wr[p];
  __syncthreads();

  f32x4 acc[4][4];
#pragma unroll
  for (int i = 0; i < 4; ++i)
#pragma unroll
    for (int mh = 0; mh < 4; ++mh) acc[i][mh] = f32x4{0.f, 0.f, 0.f, 0.f};

  for (int ks = 0; ks < 8; ++ks) {
    const int cur = ks & 1;
    if (ks < 7) {
      xr = *(const bf16x8*)(xsrc + (ks + 1) * 32);
#pragma unroll
      for (int p = 0; p < 4; ++p)
        wr[p] = *(const bf16x8*)(wsrc + (size_t)p * 64 * 256 + (ks + 1) * 32);
    }
    bf16x8 wf[4], xf[4];
#pragma unroll
    for (int i = 0; i < 4; ++i)
      wf[i] = *(const bf16x8*)&Ws[cur][((nt0 + i) * 16 + l15) * 32 + l4 * 8];
#pragma unroll
    for (int mh = 0; mh < 4; ++mh)
      xf[mh] = *(const bf16x8*)&Xs[cur][(mh * 16 + l15) * 32 + l4 * 8];
#pragma unroll
    for (int i = 0; i < 4; ++i)
#pragma unroll
      for (int mh = 0; mh < 4; ++mh)
        acc[i][mh] = mfma16(wf[i], xf[mh], acc[i][mh]);
    if (ks < 7) {
      short* xd = (cur ? xdst0 : xdst1);
      short* wd = (cur ? wdst0 : wdst1);
      *(bf16x8*)xd = xr;
#pragma unroll
      for (int p = 0; p < 4; ++p) *(bf16x8*)(wd + p * 2048) = wr[p];
    }
    __syncthreads();
  }

#pragma unroll
  for (int i = 0; i < 4; ++i) {
    const int n0 = (nt0 + i) * 16 + l4 * 4;
    float4 bi = *(const float4*)(bo + n0);
#pragma unroll
    for (int mh = 0; mh < 4; ++mh) {
      const int m = bx * 64 + mh * 16 + l15;
      float4 r;
      r.x = acc[i][mh][0] + bi.x;
      r.y = acc[i][mh][1] + bi.y;
      r.z = acc[i][mh][2] + bi.z;
      r.w = acc[i][mh][3] + bi.w;
      *(float4*)(out + (size_t)m * 256 + n0) = r;
    }
  }
}

// ---------------------------------------------------------------------------
// Flash attention v12: identical to the passing v11 (split-KV x2 via
// blockIdx.y, fp32 partials, packed [32][128] LDS tiles, double-buffered)
// EXCEPT __launch_bounds__(256, 3): the (256,4) 128-reg unified cap forced
// a 64/64 arch/acc split and massive scratch spill (R11: 948 MB HBM traffic,
// VGPR=64). (256,3) caps ~170, fits the ~130-reg footprint, 3 blocks/CU.
// ---------------------------------------------------------------------------
__global__ __launch_bounds__(256, 3) void attn_kernel12(
    const short* __restrict__ Q, const short* __restrict__ K,
    const short* __restrict__ VT, float* __restrict__ Opart,
    float* __restrict__ lpart) {
  const int lin = blockIdx.x;        // 512
  const int bh = lin & 31;           // same-bh blocks land on same XCD
  const int qt = lin >> 5;           // 0..15
  const int sp = blockIdx.y;         // split 0/1
  const int tid = threadIdx.x, wid = tid >> 6, lane = tid & 63;
  const int q31 = lane & 31, h = lane >> 5;
  constexpr int NT = 16;  // KV tiles per split

  __shared__ short Ks[2][32 * 128];  // packed [64][64] tiles
  __shared__ short Vs[2][32 * 128];

  const short* Kgs = K + (size_t)bh * S * HD + (size_t)sp * 1024 * HD;
  const short* Vg = VT + (size_t)bh * HD * S;
  const int vcol0 = sp * 1024;
  const int qrow = qt * 128 + wid * 32;

  const short* Qg = Q + ((size_t)bh * S + qrow + q31) * HD + h * 8;
  bf16x8 qf[4];
#pragma unroll
  for (int ds = 0; ds < 4; ++ds) qf[ds] = *(const bf16x8*)(Qg + ds * 16);

  bf16x8 ones;
#pragma unroll
  for (int i = 0; i < 8; ++i) ones[i] = (short)0x3F80;

  // staging addresses (packed): logical row srow 0..63
  const int srow = tid >> 2;
  const int pr = srow & 31;
  const int scol = (tid & 3) * 16;
  const int cb0 = ((srow >> 5) << 6) + scol;  // half-select bit 6
  const int swz = (pr & 15) * 8;
  const int c0 = cb0 ^ swz;
  const int c1 = (cb0 + 8) ^ swz;
  const int sbase = pr * 128;

  // fragment read cols: logical rows q31 (half0) / 32+q31 (half1), same phys row
  const int fs = (q31 & 15) * 8;
  int colA[4], colB[4];
#pragma unroll
  for (int ds = 0; ds < 4; ++ds) {
    colA[ds] = (ds * 16 + h * 8) ^ fs;
    colB[ds] = (64 + ds * 16 + h * 8) ^ fs;
  }
  const int rbase = q31 * 128;

  // ---- prologue: stage K(0),V(0) -> buf0; load K(1),V(1) ----
  bf16x8 kr0, kr1, vr0, vr1;
  kr0 = *(const bf16x8*)(Kgs + (size_t)srow * HD + scol);
  kr1 = *(const bf16x8*)(Kgs + (size_t)srow * HD + scol + 8);
  vr0 = *(const bf16x8*)(Vg + (size_t)srow * S + vcol0 + scol);
  vr1 = *(const bf16x8*)(Vg + (size_t)srow * S + vcol0 + scol + 8);
  *(bf16x8*)&Ks[0][sbase + c0] = kr0;
  *(bf16x8*)&Ks[0][sbase + c1] = kr1;
  *(bf16x8*)&Vs[0][sbase + c0] = vr0;
  *(bf16x8*)&Vs[0][sbase + c1] = vr1;
  {
    const short* Kn = Kgs + (size_t)64 * HD;
    kr0 = *(const bf16x8*)(Kn + (size_t)srow * HD + scol);
    kr1 = *(const bf16x8*)(Kn + (size_t)srow * HD + scol + 8);
    vr0 = *(const bf16x8*)(Vg + (size_t)srow * S + vcol0 + 64 + scol);
    vr1 = *(const bf16x8*)(Vg + (size_t)srow * S + vcol0 + 64 + scol + 8);
  }
  __syncthreads();

  f32x16 o0, o1, lsum;
#pragma unroll
  for (int i = 0; i < 16; ++i) { o0[i] = 0.f; o1[i] = 0.f; lsum[i] = 0.f; }
  bf16x8 pB[4];

#define EXPPACK(S0, S1)                                               \
  {                                                                   \
    _Pragma("unroll") for (int win = 0; win < 2; ++win) {             \
      const f32x16& sc = win ? (S1) : (S0);                           \
      float p[16];                                                    \
      _Pragma("unroll") for (int r = 0; r < 16; ++r)                  \
          p[r] = exp2a(sc[r]);                                        \
      unsigned w[8];                                                  \
      _Pragma("unroll") for (int i = 0; i < 8; ++i)                   \
          w[i] = cvtpk(p[2 * i], p[2 * i + 1]);                       \
      unsigned x0 = w[0], y0 = w[2], x1 = w[1], y1 = w[3];            \
      unsigned x2 = w[4], y2 = w[6], x3 = w[5], y3 = w[7];            \
      asm("v_permlane32_swap_b32 %0, %1" : "+v"(x0), "+v"(y0));       \
      asm("v_permlane32_swap_b32 %0, %1" : "+v"(x1), "+v"(y1));       \
      asm("v_permlane32_swap_b32 %0, %1" : "+v"(x2), "+v"(y2));       \
      asm("v_permlane32_swap_b32 %0, %1" : "+v"(x3), "+v"(y3));       \
      uint4v u0 = {x0, x1, y0, y1};                                   \
      uint4v u1 = {x2, x3, y2, y3};                                   \
      __builtin_memcpy(&pB[win * 2 + 0], &u0, 16);                    \
      __builtin_memcpy(&pB[win * 2 + 1], &u1, 16);                    \
    }                                                                 \
  }

  // ---- peeled iteration 0: QK(0); exp(0); B1; write K(1),V(1)->buf1; B2 ----
  {
    f32x16 sc0, sc1;
#pragma unroll
    for (int i = 0; i < 16; ++i) { sc0[i] = 0.f; sc1[i] = 0.f; }
    __builtin_amdgcn_s_setprio(1);
#pragma unroll
    for (int ds = 0; ds < 4; ++ds) {
      bf16x8 k0 = *(const bf16x8*)&Ks[0][rbase + colA[ds]];
      bf16x8 k1 = *(const bf16x8*)&Ks[0][rbase + colB[ds]];
      sc0 = mfma32(k0, qf[ds], sc0);
      sc1 = mfma32(k1, qf[ds], sc1);
    }
    __builtin_amdgcn_s_setprio(0);
    EXPPACK(sc0, sc1);
    __syncthreads();
    *(bf16x8*)&Ks[1][sbase + c0] = kr0;
    *(bf16x8*)&Ks[1][sbase + c1] = kr1;
    *(bf16x8*)&Vs[1][sbase + c0] = vr0;
    *(bf16x8*)&Vs[1][sbase + c1] = vr1;
    __syncthreads();
  }

  // ---- main loop t = 1 .. NT-1 (invariants: Ks[cur]=K(t), Vs[prv]=V(t-1)) ----
  for (int kt = 1; kt < NT; ++kt) {
    const int cur = kt & 1, prv = cur ^ 1;
    if (kt + 1 < NT) {
      const short* Kn = Kgs + (size_t)(kt + 1) * 64 * HD;
      kr0 = *(const bf16x8*)(Kn + (size_t)srow * HD + scol);
      kr1 = *(const bf16x8*)(Kn + (size_t)srow * HD + scol + 8);
      vr0 = *(const bf16x8*)(Vg + (size_t)srow * S + vcol0 + (kt + 1) * 64 + scol);
      vr1 = *(const bf16x8*)(Vg + (size_t)srow * S + vcol0 + (kt + 1) * 64 + scol + 8);
    }

    f32x16 sc0, sc1;
#pragma unroll
    for (int i = 0; i < 16; ++i) { sc0[i] = 0.f; sc1[i] = 0.f; }

    __builtin_amdgcn_s_setprio(1);
#pragma unroll
    for (int ds = 0; ds < 4; ++ds) {
      bf16x8 k0 = *(const bf16x8*)&Ks[cur][rbase + colA[ds]];
      bf16x8 k1 = *(const bf16x8*)&Ks[cur][rbase + colB[ds]];
      sc0 = mfma32(k0, qf[ds], sc0);
      sc1 = mfma32(k1, qf[ds], sc1);
      bf16x8 v0 = *(const bf16x8*)&Vs[prv][rbase + colA[ds]];
      bf16x8 v1 = *(const bf16x8*)&Vs[prv][rbase + colB[ds]];
      o0 = mfma32(v0, pB[ds], o0);
      o1 = mfma32(v1, pB[ds], o1);
      lsum = mfma32(ones, pB[ds], lsum);
    }
    __builtin_amdgcn_s_setprio(0);

    EXPPACK(sc0, sc1);
    __syncthreads();  // B1: reads of buf[prv]/buf[cur] done
    if (kt + 1 < NT) {
      *(bf16x8*)&Ks[prv][sbase + c0] = kr0;
      *(bf16x8*)&Ks[prv][sbase + c1] = kr1;
      *(bf16x8*)&Vs[prv][sbase + c0] = vr0;
      *(bf16x8*)&Vs[prv][sbase + c1] = vr1;
    }
    __syncthreads();  // B2: writes visible
  }

  // ---- epilogue: PV(NT-1) from Vs[(NT-1)&1]; pB = P(NT-1) ----
  {
    const int cur = (NT - 1) & 1;
    __builtin_amdgcn_s_setprio(1);
#pragma unroll
    for (int ds = 0; ds < 4; ++ds) {
      bf16x8 v0 = *(const bf16x8*)&Vs[cur][rbase + colA[ds]];
      bf16x8 v1 = *(const bf16x8*)&Vs[cur][rbase + colB[ds]];
      o0 = mfma32(v0, pB[ds], o0);
      o1 = mfma32(v1, pB[ds], o1);
      lsum = mfma32(ones, pB[ds], lsum);
    }
    __builtin_amdgcn_s_setprio(0);
  }
#undef EXPPACK

  // ---- write fp32 partial O + l: layout [sp][bh][q][64] ----
  float* op = Opart + (((size_t)sp * 32 + bh) * 2048 + qrow + q31) * 64;
#pragma unroll
  for (int dt = 0; dt < 2; ++dt) {
    const f32x16& o = dt ? o1 : o0;
#pragma unroll
    for (int g = 0; g < 4; ++g) {
      const int d0 = dt * 32 + 8 * g + 4 * h;
      float4 r;
      r.x = o[4 * g + 0];
      r.y = o[4 * g + 1];
      r.z = o[4 * g + 2];
      r.w = o[4 * g + 3];
      *(float4*)(op + d0) = r;
    }
  }
  if (lane < 32) {
    lpart[((size_t)sp * 32 + bh) * 2048 + qrow + q31] = lsum[0];
  }
}

}  // namespace

extern "C" void kernel_launch(void* const* d_in, const int* in_sizes, int n_in,
                              void* d_out, int out_size, void* d_ws, size_t ws_size,
                              hipStream_t stream) {
  const float* x  = (const float*)d_in[0];
  const float* Wq = (const float*)d_in[1];
  const float* bq = (const float*)d_in[2];
  const float* Wk = (const float*)d_in[3];
  const float* bk = (const float*)d_in[4];
  const float* Wv = (const float*)d_in[5];
  const float* bv = (const float*)d_in[6];
  const float* Wo = (const float*)d_in[7];
  const float* bo = (const float*)d_in[8];
  float* out = (float*)d_out;

  const size_t per = (size_t)M * D;  // 4,194,304 elems
  short* WqT = (short*)d_ws;
  short* WkT = WqT + 256 * 256;
  short* WvT = WkT + 256 * 256;
  short* WoT = WvT + 256 * 256;
  short* Qbf = WoT + 256 * 256;
  short* Kbf = Qbf + per;
  short* Vt  = Kbf + per;            // [bh][d][s] bf16
  float* Op0 = (float*)(Vt + per);   // partial O split 0 (fp32)
  float* Op1 = Op0 + per;            // partial O split 1 (fp32)
  float* lp  = Op1 + per;            // l partials [2][32][2048] f32
  float* lp0 = lp;
  float* lp1 = lp + 32 * 2048;
  short* Abf = Qbf;                  // alias: Q dead after attn

  prep_w_kernel<<<64, 256, 0, stream>>>(Wq, Wk, Wv, Wo, WqT, WkT, WvT, WoT);
  gemm_qkv_kernel<<<dim3(256, 3), 256, 0, stream>>>(x, WqT, WkT, WvT, bq, bk, bv,
                                                    Qbf, Kbf, Vt);
  attn_kernel12<<<dim3(512, 2), 256, 0, stream>>>(Qbf, Kbf, Vt, Op0, lp);
  merge_kernel<<<2048, 256, 0, stream>>>(Op0, Op1, lp0, lp1, Abf);
  gemm_out_kernel<<<256, 256, 0, stream>>>(Abf, WoT, bo, out);
}

// Round 13
// 126.695 us; speedup vs baseline: 1.9392x; 1.0011x over previous
//
#include <hip/hip_runtime.h>
#include <hip/hip_bf16.h>

namespace {

constexpr int B_ = 8, S = 2048, D = 256, H = 4, HD = 64;
constexpr int M = B_ * S;  // 16384

typedef __attribute__((ext_vector_type(8))) short bf16x8;
typedef __attribute__((ext_vector_type(4))) short bf16x4;
typedef __attribute__((ext_vector_type(4))) float f32x4;
typedef __attribute__((ext_vector_type(16))) float f32x16;
typedef __attribute__((ext_vector_type(4))) unsigned uint4v;

__device__ inline short f2bf(float x) {
  __hip_bfloat16 h = __float2bfloat16(x);
  short s;
  __builtin_memcpy(&s, &h, 2);
  return s;
}

__device__ inline f32x4 mfma16(bf16x8 a, bf16x8 b, f32x4 c) {
  return __builtin_amdgcn_mfma_f32_16x16x32_bf16(a, b, c, 0, 0, 0);
}
__device__ inline f32x16 mfma32(bf16x8 a, bf16x8 b, f32x16 c) {
  return __builtin_amdgcn_mfma_f32_32x32x16_bf16(a, b, c, 0, 0, 0);
}

// raw 2^x
__device__ inline float exp2a(float x) {
  float r;
  asm("v_exp_f32 %0, %1" : "=v"(r) : "v"(x));
  return r;
}

// HW packed f32x2 -> bf16x2 (RNE)
__device__ inline unsigned cvtpk(float lo, float hi) {
  unsigned r;
  asm("v_cvt_pk_bf16_f32 %0, %1, %2" : "=v"(r) : "v"(lo), "v"(hi));
  return r;
}

__device__ inline bf16x4 pk4(float a, float b, float c, float d) {
  unsigned lo = cvtpk(a, b), hi = cvtpk(c, d);
  uint2 u{lo, hi};
  bf16x4 r;
  __builtin_memcpy(&r, &u, 8);
  return r;
}

// load 8 fp32, convert to bf16x8
__device__ inline bf16x8 ld_cvt8(const float* p) {
  float4 a = *(const float4*)p;
  float4 b = *(const float4*)(p + 4);
  uint4v u = {cvtpk(a.x, a.y), cvtpk(a.z, a.w), cvtpk(b.x, b.y), cvtpk(b.z, b.w)};
  bf16x8 r;
  __builtin_memcpy(&r, &u, 16);
  return r;
}

// ---------------------------------------------------------------------------
// Prep: 64 blocks transpose W{q,k,v,o} fp32[k][n] -> bf16 Wt[n][k].
// ---------------------------------------------------------------------------
__global__ __launch_bounds__(256) void prep_w_kernel(
    const float* __restrict__ Wq, const float* __restrict__ Wk,
    const float* __restrict__ Wv, const float* __restrict__ Wo,
    short* __restrict__ WqT, short* __restrict__ WkT,
    short* __restrict__ WvT, short* __restrict__ WoT) {
  const int blk = blockIdx.x, t = threadIdx.x;
  const int wq = blk >> 4, n0 = (blk & 15) * 16;
  const float* W = wq == 0 ? Wq : wq == 1 ? Wk : wq == 2 ? Wv : Wo;
  short* Wt = wq == 0 ? WqT : wq == 1 ? WkT : wq == 2 ? WvT : WoT;
#pragma unroll
  for (int j4 = 0; j4 < 4; ++j4) {
    float4 v = *(const float4*)(W + (size_t)t * 256 + n0 + j4 * 4);
    Wt[(n0 + j4 * 4 + 0) * 256 + t] = f2bf(v.x);
    Wt[(n0 + j4 * 4 + 1) * 256 + t] = f2bf(v.y);
    Wt[(n0 + j4 * 4 + 2) * 256 + t] = f2bf(v.z);
    Wt[(n0 + j4 * 4 + 3) * 256 + t] = f2bf(v.w);
  }
}

// ---------------------------------------------------------------------------
// QKV GEMM: x staged fp32 -> cvt_pk -> LDS. Q scale folds 1/8*log2e;
// V written [bh][d][s] via operand swap.
// ---------------------------------------------------------------------------
__global__ __launch_bounds__(256) void gemm_qkv_kernel(
    const float* __restrict__ x,
    const short* __restrict__ WqT, const short* __restrict__ WkT,
    const short* __restrict__ WvT,
    const float* __restrict__ bq, const float* __restrict__ bk,
    const float* __restrict__ bv,
    short* __restrict__ Qo, short* __restrict__ Ko, short* __restrict__ Vt) {
  const int bx = blockIdx.x;
  const int which = blockIdx.y;
  const short* Wt = which == 0 ? WqT : which == 1 ? WkT : WvT;
  const float* bias = which == 0 ? bq : which == 1 ? bk : bv;

  __shared__ short Xs[2][64 * 32];
  __shared__ short Ws[2][256 * 32];

  const int tid = threadIdx.x;
  const int wid = tid >> 6, lane = tid & 63;
  const int l15 = lane & 15, l4 = lane >> 4;
  const int nt0 = wid * 4;

  const float* xsrc = x + ((size_t)(bx * 64 + (tid >> 2))) * 256 + (tid & 3) * 8;
  const short* wsrc = Wt + ((size_t)(tid >> 2)) * 256 + (tid & 3) * 8;
  short* xdst0 = &Xs[0][tid * 8];
  short* xdst1 = &Xs[1][tid * 8];
  short* wdst0 = &Ws[0][tid * 8];
  short* wdst1 = &Ws[1][tid * 8];

  bf16x8 xr, wr[4];
  xr = ld_cvt8(xsrc);
#pragma unroll
  for (int p = 0; p < 4; ++p) wr[p] = *(const bf16x8*)(wsrc + (size_t)p * 64 * 256);
  *(bf16x8*)xdst0 = xr;
#pragma unroll
  for (int p = 0; p < 4; ++p) *(bf16x8*)(wdst0 + p * 2048) = wr[p];
  __syncthreads();

  f32x4 acc[4][4];
#pragma unroll
  for (int i = 0; i < 4; ++i)
#pragma unroll
    for (int mh = 0; mh < 4; ++mh) acc[i][mh] = f32x4{0.f, 0.f, 0.f, 0.f};

  for (int ks = 0; ks < 8; ++ks) {
    const int cur = ks & 1;
    if (ks < 7) {
      xr = ld_cvt8(xsrc + (ks + 1) * 32);
#pragma unroll
      for (int p = 0; p < 4; ++p)
        wr[p] = *(const bf16x8*)(wsrc + (size_t)p * 64 * 256 + (ks + 1) * 32);
    }
    bf16x8 wf[4], xf[4];
#pragma unroll
    for (int i = 0; i < 4; ++i)
      wf[i] = *(const bf16x8*)&Ws[cur][((nt0 + i) * 16 + l15) * 32 + l4 * 8];
#pragma unroll
    for (int mh = 0; mh < 4; ++mh)
      xf[mh] = *(const bf16x8*)&Xs[cur][(mh * 16 + l15) * 32 + l4 * 8];
    if (which == 2) {
#pragma unroll
      for (int i = 0; i < 4; ++i)
#pragma unroll
        for (int mh = 0; mh < 4; ++mh)
          acc[i][mh] = mfma16(xf[mh], wf[i], acc[i][mh]);  // D[m][n]
    } else {
#pragma unroll
      for (int i = 0; i < 4; ++i)
#pragma unroll
        for (int mh = 0; mh < 4; ++mh)
          acc[i][mh] = mfma16(wf[i], xf[mh], acc[i][mh]);  // D[n][m]
    }
    if (ks < 7) {
      short* xd = (cur ? xdst0 : xdst1);
      short* wd = (cur ? wdst0 : wdst1);
      *(bf16x8*)xd = xr;
#pragma unroll
      for (int p = 0; p < 4; ++p) *(bf16x8*)(wd + p * 2048) = wr[p];
    }
    __syncthreads();
  }

  if (which == 2) {
    const int m0 = bx * 64 + l4 * 4;
#pragma unroll
    for (int i = 0; i < 4; ++i) {
      const int n = (nt0 + i) * 16 + l15;
      const float bi = bias[n];
      const int h = n >> 6, d = n & 63;
#pragma unroll
      for (int mh = 0; mh < 4; ++mh) {
        const int m = m0 + mh * 16;
        const int bb = m >> 11, s0 = m & 2047;
        bf16x4 r = pk4(acc[i][mh][0] + bi, acc[i][mh][1] + bi,
                       acc[i][mh][2] + bi, acc[i][mh][3] + bi);
        *(bf16x4*)(Vt + (((size_t)bb * H + h) * HD + d) * S + s0) = r;
      }
    }
  } else {
    const float scale = which == 0 ? 0.18033688011112042f : 1.0f;  // 1/8*log2e
    short* outp = which == 0 ? Qo : Ko;
#pragma unroll
    for (int i = 0; i < 4; ++i) {
      const int n0 = (nt0 + i) * 16 + l4 * 4;
      float4 bi = *(const float4*)(bias + n0);
      const int h = n0 >> 6, d0 = n0 & 63;
#pragma unroll
      for (int mh = 0; mh < 4; ++mh) {
        const int m = bx * 64 + mh * 16 + l15;
        const int bb = m >> 11, s = m & 2047;
        bf16x4 r = pk4((acc[i][mh][0] + bi.x) * scale, (acc[i][mh][1] + bi.y) * scale,
                       (acc[i][mh][2] + bi.z) * scale, (acc[i][mh][3] + bi.w) * scale);
        *(bf16x4*)(outp + (((size_t)bb * H + h) * S + s) * HD + d0) = r;
      }
    }
  }
}

// ---------------------------------------------------------------------------
// Split-KV merge: Abf[m][256] = round_bf16((O0+O1) / (l0+l1)).
// Opart layout [sp][bh][q][64] fp32; lpart [sp][bh][2048] fp32.
// ---------------------------------------------------------------------------
__global__ __launch_bounds__(256) void merge_kernel(
    const float* __restrict__ O0, const float* __restrict__ O1,
    const float* __restrict__ l0, const float* __restrict__ l1,
    short* __restrict__ Abf) {
  const size_t g = ((size_t)blockIdx.x * 256 + threadIdx.x) * 8;  // over 32*2048*64
  const int bh = (int)(g >> 17);
  const int rem = (int)(g & 131071);
  const int q = rem >> 6, d = rem & 63;
  const float iv = 1.0f / (l0[(size_t)bh * 2048 + q] + l1[(size_t)bh * 2048 + q]);
  float4 a0 = *(const float4*)(O0 + g);
  float4 a1 = *(const float4*)(O0 + g + 4);
  float4 b0 = *(const float4*)(O1 + g);
  float4 b1 = *(const float4*)(O1 + g + 4);
  uint4v u = {cvtpk((a0.x + b0.x) * iv, (a0.y + b0.y) * iv),
              cvtpk((a0.z + b0.z) * iv, (a0.w + b0.w) * iv),
              cvtpk((a1.x + b1.x) * iv, (a1.y + b1.y) * iv),
              cvtpk((a1.z + b1.z) * iv, (a1.w + b1.w) * iv)};
  bf16x8 r;
  __builtin_memcpy(&r, &u, 16);
  const int b = bh >> 2, h = bh & 3;
  *(bf16x8*)(Abf + ((size_t)b * 2048 + q) * 256 + h * 64 + d) = r;
}

// ---------------------------------------------------------------------------
// Out projection GEMM (bf16 A in, fp32 out)
// ---------------------------------------------------------------------------
__global__ __launch_bounds__(256) void gemm_out_kernel(
    const short* __restrict__ Abf, const short* __restrict__ WoT,
    const float* __restrict__ bo, float* __restrict__ out) {
  const int bx = blockIdx.x;
  __shared__ short Xs[2][64 * 32];
  __shared__ short Ws[2][256 * 32];

  const int tid = threadIdx.x;
  const int wid = tid >> 6, lane = tid & 63;
  const int l15 = lane & 15, l4 = lane >> 4;
  const int nt0 = wid * 4;

  const short* xsrc = Abf + ((size_t)(bx * 64 + (tid >> 2))) * 256 + (tid & 3) * 8;
  const short* wsrc = WoT + ((size_t)(tid >> 2)) * 256 + (tid & 3) * 8;
  short* xdst0 = &Xs[0][tid * 8];
  short* xdst1 = &Xs[1][tid * 8];
  short* wdst0 = &Ws[0][tid * 8];
  short* wdst1 = &Ws[1][tid * 8];

  bf16x8 xr, wr[4];
  xr = *(const bf16x8*)xsrc;
#pragma unroll
  for (int p = 0; p < 4; ++p) wr[p] = *(const bf16x8*)(wsrc + (size_t)p * 64 * 256);
  *(bf16x8*)xdst0 = xr;
#pragma unroll
  for (int p = 0; p < 4; ++p) *(bf16x8*)(wdst0 + p * 2048) = wr[p];
  __syncthreads();

  f32x4 acc[4][4];
#pragma unroll
  for (int i = 0; i < 4; ++i)
#pragma unroll
    for (int mh = 0; mh < 4; ++mh) acc[i][mh] = f32x4{0.f, 0.f, 0.f, 0.f};

  for (int ks = 0; ks < 8; ++ks) {
    const int cur = ks & 1;
    if (ks < 7) {
      xr = *(const bf16x8*)(xsrc + (ks + 1) * 32);
#pragma unroll
      for (int p = 0; p < 4; ++p)
        wr[p] = *(const bf16x8*)(wsrc + (size_t)p * 64 * 256 + (ks + 1) * 32);
    }
    bf16x8 wf[4], xf[4];
#pragma unroll
    for (int i = 0; i < 4; ++i)
      wf[i] = *(const bf16x8*)&Ws[cur][((nt0 + i) * 16 + l15) * 32 + l4 * 8];
#pragma unroll
    for (int mh = 0; mh < 4; ++mh)
      xf[mh] = *(const bf16x8*)&Xs[cur][(mh * 16 + l15) * 32 + l4 * 8];
#pragma unroll
    for (int i = 0; i < 4; ++i)
#pragma unroll
      for (int mh = 0; mh < 4; ++mh)
        acc[i][mh] = mfma16(wf[i], xf[mh], acc[i][mh]);
    if (ks < 7) {
      short* xd = (cur ? xdst0 : xdst1);
      short* wd = (cur ? wdst0 : wdst1);
      *(bf16x8*)xd = xr;
#pragma unroll
      for (int p = 0; p < 4; ++p) *(bf16x8*)(wd + p * 2048) = wr[p];
    }
    __syncthreads();
  }

#pragma unroll
  for (int i = 0; i < 4; ++i) {
    const int n0 = (nt0 + i) * 16 + l4 * 4;
    float4 bi = *(const float4*)(bo + n0);
#pragma unroll
    for (int mh = 0; mh < 4; ++mh) {
      const int m = bx * 64 + mh * 16 + l15;
      float4 r;
      r.x = acc[i][mh][0] + bi.x;
      r.y = acc[i][mh][1] + bi.y;
      r.z = acc[i][mh][2] + bi.z;
      r.w = acc[i][mh][3] + bi.w;
      *(float4*)(out + (size_t)m * 256 + n0) = r;
    }
  }
}

// ---------------------------------------------------------------------------
// Flash attention v12: identical to the passing v11 (split-KV x2 via
// blockIdx.y, fp32 partials, packed [32][128] LDS tiles, double-buffered)
// EXCEPT __launch_bounds__(256, 3): the (256,4) 128-reg unified cap forced
// a 64/64 arch/acc split and massive scratch spill (R11: 948 MB HBM traffic,
// VGPR=64). (256,3) caps ~170, fits the ~130-reg footprint, 3 blocks/CU.
// ---------------------------------------------------------------------------
__global__ __launch_bounds__(256, 3) void attn_kernel12(
    const short* __restrict__ Q, const short* __restrict__ K,
    const short* __restrict__ VT, float* __restrict__ Opart,
    float* __restrict__ lpart) {
  const int lin = blockIdx.x;        // 512
  const int bh = lin & 31;           // same-bh blocks land on same XCD
  const int qt = lin >> 5;           // 0..15
  const int sp = blockIdx.y;         // split 0/1
  const int tid = threadIdx.x, wid = tid >> 6, lane = tid & 63;
  const int q31 = lane & 31, h = lane >> 5;
  constexpr int NT = 16;  // KV tiles per split

  __shared__ short Ks[2][32 * 128];  // packed [64][64] tiles
  __shared__ short Vs[2][32 * 128];

  const short* Kgs = K + (size_t)bh * S * HD + (size_t)sp * 1024 * HD;
  const short* Vg = VT + (size_t)bh * HD * S;
  const int vcol0 = sp * 1024;
  const int qrow = qt * 128 + wid * 32;

  const short* Qg = Q + ((size_t)bh * S + qrow + q31) * HD + h * 8;
  bf16x8 qf[4];
#pragma unroll
  for (int ds = 0; ds < 4; ++ds) qf[ds] = *(const bf16x8*)(Qg + ds * 16);

  bf16x8 ones;
#pragma unroll
  for (int i = 0; i < 8; ++i) ones[i] = (short)0x3F80;

  // staging addresses (packed): logical row srow 0..63
  const int srow = tid >> 2;
  const int pr = srow & 31;
  const int scol = (tid & 3) * 16;
  const int cb0 = ((srow >> 5) << 6) + scol;  // half-select bit 6
  const int swz = (pr & 15) * 8;
  const int c0 = cb0 ^ swz;
  const int c1 = (cb0 + 8) ^ swz;
  const int sbase = pr * 128;

  // fragment read cols: logical rows q31 (half0) / 32+q31 (half1), same phys row
  const int fs = (q31 & 15) * 8;
  int colA[4], colB[4];
#pragma unroll
  for (int ds = 0; ds < 4; ++ds) {
    colA[ds] = (ds * 16 + h * 8) ^ fs;
    colB[ds] = (64 + ds * 16 + h * 8) ^ fs;
  }
  const int rbase = q31 * 128;

  // ---- prologue: stage K(0),V(0) -> buf0; load K(1),V(1) ----
  bf16x8 kr0, kr1, vr0, vr1;
  kr0 = *(const bf16x8*)(Kgs + (size_t)srow * HD + scol);
  kr1 = *(const bf16x8*)(Kgs + (size_t)srow * HD + scol + 8);
  vr0 = *(const bf16x8*)(Vg + (size_t)srow * S + vcol0 + scol);
  vr1 = *(const bf16x8*)(Vg + (size_t)srow * S + vcol0 + scol + 8);
  *(bf16x8*)&Ks[0][sbase + c0] = kr0;
  *(bf16x8*)&Ks[0][sbase + c1] = kr1;
  *(bf16x8*)&Vs[0][sbase + c0] = vr0;
  *(bf16x8*)&Vs[0][sbase + c1] = vr1;
  {
    const short* Kn = Kgs + (size_t)64 * HD;
    kr0 = *(const bf16x8*)(Kn + (size_t)srow * HD + scol);
    kr1 = *(const bf16x8*)(Kn + (size_t)srow * HD + scol + 8);
    vr0 = *(const bf16x8*)(Vg + (size_t)srow * S + vcol0 + 64 + scol);
    vr1 = *(const bf16x8*)(Vg + (size_t)srow * S + vcol0 + 64 + scol + 8);
  }
  __syncthreads();

  f32x16 o0, o1, lsum;
#pragma unroll
  for (int i = 0; i < 16; ++i) { o0[i] = 0.f; o1[i] = 0.f; lsum[i] = 0.f; }
  bf16x8 pB[4];

#define EXPPACK(S0, S1)                                               \
  {                                                                   \
    _Pragma("unroll") for (int win = 0; win < 2; ++win) {             \
      const f32x16& sc = win ? (S1) : (S0);                           \
      float p[16];                                                    \
      _Pragma("unroll") for (int r = 0; r < 16; ++r)                  \
          p[r] = exp2a(sc[r]);                                        \
      unsigned w[8];                                                  \
      _Pragma("unroll") for (int i = 0; i < 8; ++i)                   \
          w[i] = cvtpk(p[2 * i], p[2 * i + 1]);                       \
      unsigned x0 = w[0], y0 = w[2], x1 = w[1], y1 = w[3];            \
      unsigned x2 = w[4], y2 = w[6], x3 = w[5], y3 = w[7];            \
      asm("v_permlane32_swap_b32 %0, %1" : "+v"(x0), "+v"(y0));       \
      asm("v_permlane32_swap_b32 %0, %1" : "+v"(x1), "+v"(y1));       \
      asm("v_permlane32_swap_b32 %0, %1" : "+v"(x2), "+v"(y2));       \
      asm("v_permlane32_swap_b32 %0, %1" : "+v"(x3), "+v"(y3));       \
      uint4v u0 = {x0, x1, y0, y1};                                   \
      uint4v u1 = {x2, x3, y2, y3};                                   \
      __builtin_memcpy(&pB[win * 2 + 0], &u0, 16);                    \
      __builtin_memcpy(&pB[win * 2 + 1], &u1, 16);                    \
    }                                                                 \
  }

  // ---- peeled iteration 0: QK(0); exp(0); B1; write K(1),V(1)->buf1; B2 ----
  {
    f32x16 sc0, sc1;
#pragma unroll
    for (int i = 0; i < 16; ++i) { sc0[i] = 0.f; sc1[i] = 0.f; }
    __builtin_amdgcn_s_setprio(1);
#pragma unroll
    for (int ds = 0; ds < 4; ++ds) {
      bf16x8 k0 = *(const bf16x8*)&Ks[0][rbase + colA[ds]];
      bf16x8 k1 = *(const bf16x8*)&Ks[0][rbase + colB[ds]];
      sc0 = mfma32(k0, qf[ds], sc0);
      sc1 = mfma32(k1, qf[ds], sc1);
    }
    __builtin_amdgcn_s_setprio(0);
    EXPPACK(sc0, sc1);
    __syncthreads();
    *(bf16x8*)&Ks[1][sbase + c0] = kr0;
    *(bf16x8*)&Ks[1][sbase + c1] = kr1;
    *(bf16x8*)&Vs[1][sbase + c0] = vr0;
    *(bf16x8*)&Vs[1][sbase + c1] = vr1;
    __syncthreads();
  }

  // ---- main loop t = 1 .. NT-1 (invariants: Ks[cur]=K(t), Vs[prv]=V(t-1)) ----
  for (int kt = 1; kt < NT; ++kt) {
    const int cur = kt & 1, prv = cur ^ 1;
    if (kt + 1 < NT) {
      const short* Kn = Kgs + (size_t)(kt + 1) * 64 * HD;
      kr0 = *(const bf16x8*)(Kn + (size_t)srow * HD + scol);
      kr1 = *(const bf16x8*)(Kn + (size_t)srow * HD + scol + 8);
      vr0 = *(const bf16x8*)(Vg + (size_t)srow * S + vcol0 + (kt + 1) * 64 + scol);
      vr1 = *(const bf16x8*)(Vg + (size_t)srow * S + vcol0 + (kt + 1) * 64 + scol + 8);
    }

    f32x16 sc0, sc1;
#pragma unroll
    for (int i = 0; i < 16; ++i) { sc0[i] = 0.f; sc1[i] = 0.f; }

    __builtin_amdgcn_s_setprio(1);
#pragma unroll
    for (int ds = 0; ds < 4; ++ds) {
      bf16x8 k0 = *(const bf16x8*)&Ks[cur][rbase + colA[ds]];
      bf16x8 k1 = *(const bf16x8*)&Ks[cur][rbase + colB[ds]];
      sc0 = mfma32(k0, qf[ds], sc0);
      sc1 = mfma32(k1, qf[ds], sc1);
      bf16x8 v0 = *(const bf16x8*)&Vs[prv][rbase + colA[ds]];
      bf16x8 v1 = *(const bf16x8*)&Vs[prv][rbase + colB[ds]];
      o0 = mfma32(v0, pB[ds], o0);
      o1 = mfma32(v1, pB[ds], o1);
      lsum = mfma32(ones, pB[ds], lsum);
    }
    __builtin_amdgcn_s_setprio(0);

    EXPPACK(sc0, sc1);
    __syncthreads();  // B1: reads of buf[prv]/buf[cur] done
    if (kt + 1 < NT) {
      *(bf16x8*)&Ks[prv][sbase + c0] = kr0;
      *(bf16x8*)&Ks[prv][sbase + c1] = kr1;
      *(bf16x8*)&Vs[prv][sbase + c0] = vr0;
      *(bf16x8*)&Vs[prv][sbase + c1] = vr1;
    }
    __syncthreads();  // B2: writes visible
  }

  // ---- epilogue: PV(NT-1) from Vs[(NT-1)&1]; pB = P(NT-1) ----
  {
    const int cur = (NT - 1) & 1;
    __builtin_amdgcn_s_setprio(1);
#pragma unroll
    for (int ds = 0; ds < 4; ++ds) {
      bf16x8 v0 = *(const bf16x8*)&Vs[cur][rbase + colA[ds]];
      bf16x8 v1 = *(const bf16x8*)&Vs[cur][rbase + colB[ds]];
      o0 = mfma32(v0, pB[ds], o0);
      o1 = mfma32(v1, pB[ds], o1);
      lsum = mfma32(ones, pB[ds], lsum);
    }
    __builtin_amdgcn_s_setprio(0);
  }
#undef EXPPACK

  // ---- write fp32 partial O + l: layout [sp][bh][q][64] ----
  float* op = Opart + (((size_t)sp * 32 + bh) * 2048 + qrow + q31) * 64;
#pragma unroll
  for (int dt = 0; dt < 2; ++dt) {
    const f32x16& o = dt ? o1 : o0;
#pragma unroll
    for (int g = 0; g < 4; ++g) {
      const int d0 = dt * 32 + 8 * g + 4 * h;
      float4 r;
      r.x = o[4 * g + 0];
      r.y = o[4 * g + 1];
      r.z = o[4 * g + 2];
      r.w = o[4 * g + 3];
      *(float4*)(op + d0) = r;
    }
  }
  if (lane < 32) {
    lpart[((size_t)sp * 32 + bh) * 2048 + qrow + q31] = lsum[0];
  }
}

}  // namespace

extern "C" void kernel_launch(void* const* d_in, const int* in_sizes, int n_in,
                              void* d_out, int out_size, void* d_ws, size_t ws_size,
                              hipStream_t stream) {
  const float* x  = (const float*)d_in[0];
  const float* Wq = (const float*)d_in[1];
  const float* bq = (const float*)d_in[2];
  const float* Wk = (const float*)d_in[3];
  const float* bk = (const float*)d_in[4];
  const float* Wv = (const float*)d_in[5];
  const float* bv = (const float*)d_in[6];
  const float* Wo = (const float*)d_in[7];
  const float* bo = (const float*)d_in[8];
  float* out = (float*)d_out;

  const size_t per = (size_t)M * D;  // 4,194,304 elems
  short* WqT = (short*)d_ws;
  short* WkT = WqT + 256 * 256;
  short* WvT = WkT + 256 * 256;
  short* WoT = WvT + 256 * 256;
  short* Qbf = WoT + 256 * 256;
  short* Kbf = Qbf + per;
  short* Vt  = Kbf + per;            // [bh][d][s] bf16
  float* Op0 = (float*)(Vt + per);   // partial O split 0 (fp32)
  float* Op1 = Op0 + per;            // partial O split 1 (fp32)
  float* lp  = Op1 + per;            // l partials [2][32][2048] f32
  float* lp0 = lp;
  float* lp1 = lp + 32 * 2048;
  short* Abf = Qbf;                  // alias: Q dead after attn

  prep_w_kernel<<<64, 256, 0, stream>>>(Wq, Wk, Wv, Wo, WqT, WkT, WvT, WoT);
  gemm_qkv_kernel<<<dim3(256, 3), 256, 0, stream>>>(x, WqT, WkT, WvT, bq, bk, bv,
                                                    Qbf, Kbf, Vt);
  attn_kernel12<<<dim3(512, 2), 256, 0, stream>>>(Qbf, Kbf, Vt, Op0, lp);
  merge_kernel<<<2048, 256, 0, stream>>>(Op0, Op1, lp0, lp1, Abf);
  gemm_out_kernel<<<256, 256, 0, stream>>>(Abf, WoT, bo, out);
}

// Round 14
// 88.793 us; speedup vs baseline: 2.7669x; 1.4269x over previous
//
#include <hip/hip_runtime.h>
#include <hip/hip_bf16.h>

namespace {

constexpr int B_ = 8, S = 2048, D = 256, H = 4, HD = 64;
constexpr int M = B_ * S;  // 16384

typedef __attribute__((ext_vector_type(8))) short bf16x8;
typedef __attribute__((ext_vector_type(4))) short bf16x4;
typedef __attribute__((ext_vector_type(4))) float f32x4;
typedef __attribute__((ext_vector_type(16))) float f32x16;
typedef __attribute__((ext_vector_type(4))) unsigned uint4v;

__device__ inline short f2bf(float x) {
  __hip_bfloat16 h = __float2bfloat16(x);
  short s;
  __builtin_memcpy(&s, &h, 2);
  return s;
}

__device__ inline f32x4 mfma16(bf16x8 a, bf16x8 b, f32x4 c) {
  return __builtin_amdgcn_mfma_f32_16x16x32_bf16(a, b, c, 0, 0, 0);
}
__device__ inline f32x16 mfma32(bf16x8 a, bf16x8 b, f32x16 c) {
  return __builtin_amdgcn_mfma_f32_32x32x16_bf16(a, b, c, 0, 0, 0);
}

// raw 2^x
__device__ inline float exp2a(float x) {
  float r;
  asm("v_exp_f32 %0, %1" : "=v"(r) : "v"(x));
  return r;
}

// HW packed f32x2 -> bf16x2 (RNE)
__device__ inline unsigned cvtpk(float lo, float hi) {
  unsigned r;
  asm("v_cvt_pk_bf16_f32 %0, %1, %2" : "=v"(r) : "v"(lo), "v"(hi));
  return r;
}

__device__ inline bf16x4 pk4(float a, float b, float c, float d) {
  unsigned lo = cvtpk(a, b), hi = cvtpk(c, d);
  uint2 u{lo, hi};
  bf16x4 r;
  __builtin_memcpy(&r, &u, 8);
  return r;
}

// load 8 fp32, convert to bf16x8
__device__ inline bf16x8 ld_cvt8(const float* p) {
  float4 a = *(const float4*)p;
  float4 b = *(const float4*)(p + 4);
  uint4v u = {cvtpk(a.x, a.y), cvtpk(a.z, a.w), cvtpk(b.x, b.y), cvtpk(b.z, b.w)};
  bf16x8 r;
  __builtin_memcpy(&r, &u, 16);
  return r;
}

// ---------------------------------------------------------------------------
// Prep: 64 blocks transpose W{q,k,v,o} fp32[k][n] -> bf16 Wt[n][k].
// ---------------------------------------------------------------------------
__global__ __launch_bounds__(256) void prep_w_kernel(
    const float* __restrict__ Wq, const float* __restrict__ Wk,
    const float* __restrict__ Wv, const float* __restrict__ Wo,
    short* __restrict__ WqT, short* __restrict__ WkT,
    short* __restrict__ WvT, short* __restrict__ WoT) {
  const int blk = blockIdx.x, t = threadIdx.x;
  const int wq = blk >> 4, n0 = (blk & 15) * 16;
  const float* W = wq == 0 ? Wq : wq == 1 ? Wk : wq == 2 ? Wv : Wo;
  short* Wt = wq == 0 ? WqT : wq == 1 ? WkT : wq == 2 ? WvT : WoT;
#pragma unroll
  for (int j4 = 0; j4 < 4; ++j4) {
    float4 v = *(const float4*)(W + (size_t)t * 256 + n0 + j4 * 4);
    Wt[(n0 + j4 * 4 + 0) * 256 + t] = f2bf(v.x);
    Wt[(n0 + j4 * 4 + 1) * 256 + t] = f2bf(v.y);
    Wt[(n0 + j4 * 4 + 2) * 256 + t] = f2bf(v.z);
    Wt[(n0 + j4 * 4 + 3) * 256 + t] = f2bf(v.w);
  }
}

// ---------------------------------------------------------------------------
// QKV GEMM: x staged fp32 -> cvt_pk -> LDS. Q scale folds 1/8*log2e;
// V written [bh][d][s] via operand swap.
// ---------------------------------------------------------------------------
__global__ __launch_bounds__(256) void gemm_qkv_kernel(
    const float* __restrict__ x,
    const short* __restrict__ WqT, const short* __restrict__ WkT,
    const short* __restrict__ WvT,
    const float* __restrict__ bq, const float* __restrict__ bk,
    const float* __restrict__ bv,
    short* __restrict__ Qo, short* __restrict__ Ko, short* __restrict__ Vt) {
  const int bx = blockIdx.x;
  const int which = blockIdx.y;
  const short* Wt = which == 0 ? WqT : which == 1 ? WkT : WvT;
  const float* bias = which == 0 ? bq : which == 1 ? bk : bv;

  __shared__ short Xs[2][64 * 32];
  __shared__ short Ws[2][256 * 32];

  const int tid = threadIdx.x;
  const int wid = tid >> 6, lane = tid & 63;
  const int l15 = lane & 15, l4 = lane >> 4;
  const int nt0 = wid * 4;

  const float* xsrc = x + ((size_t)(bx * 64 + (tid >> 2))) * 256 + (tid & 3) * 8;
  const short* wsrc = Wt + ((size_t)(tid >> 2)) * 256 + (tid & 3) * 8;
  short* xdst0 = &Xs[0][tid * 8];
  short* xdst1 = &Xs[1][tid * 8];
  short* wdst0 = &Ws[0][tid * 8];
  short* wdst1 = &Ws[1][tid * 8];

  bf16x8 xr, wr[4];
  xr = ld_cvt8(xsrc);
#pragma unroll
  for (int p = 0; p < 4; ++p) wr[p] = *(const bf16x8*)(wsrc + (size_t)p * 64 * 256);
  *(bf16x8*)xdst0 = xr;
#pragma unroll
  for (int p = 0; p < 4; ++p) *(bf16x8*)(wdst0 + p * 2048) = wr[p];
  __syncthreads();

  f32x4 acc[4][4];
#pragma unroll
  for (int i = 0; i < 4; ++i)
#pragma unroll
    for (int mh = 0; mh < 4; ++mh) acc[i][mh] = f32x4{0.f, 0.f, 0.f, 0.f};

  for (int ks = 0; ks < 8; ++ks) {
    const int cur = ks & 1;
    if (ks < 7) {
      xr = ld_cvt8(xsrc + (ks + 1) * 32);
#pragma unroll
      for (int p = 0; p < 4; ++p)
        wr[p] = *(const bf16x8*)(wsrc + (size_t)p * 64 * 256 + (ks + 1) * 32);
    }
    bf16x8 wf[4], xf[4];
#pragma unroll
    for (int i = 0; i < 4; ++i)
      wf[i] = *(const bf16x8*)&Ws[cur][((nt0 + i) * 16 + l15) * 32 + l4 * 8];
#pragma unroll
    for (int mh = 0; mh < 4; ++mh)
      xf[mh] = *(const bf16x8*)&Xs[cur][(mh * 16 + l15) * 32 + l4 * 8];
    if (which == 2) {
#pragma unroll
      for (int i = 0; i < 4; ++i)
#pragma unroll
        for (int mh = 0; mh < 4; ++mh)
          acc[i][mh] = mfma16(xf[mh], wf[i], acc[i][mh]);  // D[m][n]
    } else {
#pragma unroll
      for (int i = 0; i < 4; ++i)
#pragma unroll
        for (int mh = 0; mh < 4; ++mh)
          acc[i][mh] = mfma16(wf[i], xf[mh], acc[i][mh]);  // D[n][m]
    }
    if (ks < 7) {
      short* xd = (cur ? xdst0 : xdst1);
      short* wd = (cur ? wdst0 : wdst1);
      *(bf16x8*)xd = xr;
#pragma unroll
      for (int p = 0; p < 4; ++p) *(bf16x8*)(wd + p * 2048) = wr[p];
    }
    __syncthreads();
  }

  if (which == 2) {
    const int m0 = bx * 64 + l4 * 4;
#pragma unroll
    for (int i = 0; i < 4; ++i) {
      const int n = (nt0 + i) * 16 + l15;
      const float bi = bias[n];
      const int h = n >> 6, d = n & 63;
#pragma unroll
      for (int mh = 0; mh < 4; ++mh) {
        const int m = m0 + mh * 16;
        const int bb = m >> 11, s0 = m & 2047;
        bf16x4 r = pk4(acc[i][mh][0] + bi, acc[i][mh][1] + bi,
                       acc[i][mh][2] + bi, acc[i][mh][3] + bi);
        *(bf16x4*)(Vt + (((size_t)bb * H + h) * HD + d) * S + s0) = r;
      }
    }
  } else {
    const float scale = which == 0 ? 0.18033688011112042f : 1.0f;  // 1/8*log2e
    short* outp = which == 0 ? Qo : Ko;
#pragma unroll
    for (int i = 0; i < 4; ++i) {
      const int n0 = (nt0 + i) * 16 + l4 * 4;
      float4 bi = *(const float4*)(bias + n0);
      const int h = n0 >> 6, d0 = n0 & 63;
#pragma unroll
      for (int mh = 0; mh < 4; ++mh) {
        const int m = bx * 64 + mh * 16 + l15;
        const int bb = m >> 11, s = m & 2047;
        bf16x4 r = pk4((acc[i][mh][0] + bi.x) * scale, (acc[i][mh][1] + bi.y) * scale,
                       (acc[i][mh][2] + bi.z) * scale, (acc[i][mh][3] + bi.w) * scale);
        *(bf16x4*)(outp + (((size_t)bb * H + h) * S + s) * HD + d0) = r;
      }
    }
  }
}

// ---------------------------------------------------------------------------
// Out projection GEMM (bf16 A in, fp32 out)
// ---------------------------------------------------------------------------
__global__ __launch_bounds__(256) void gemm_out_kernel(
    const short* __restrict__ Abf, const short* __restrict__ WoT,
    const float* __restrict__ bo, float* __restrict__ out) {
  const int bx = blockIdx.x;
  __shared__ short Xs[2][64 * 32];
  __shared__ short Ws[2][256 * 32];

  const int tid = threadIdx.x;
  const int wid = tid >> 6, lane = tid & 63;
  const int l15 = lane & 15, l4 = lane >> 4;
  const int nt0 = wid * 4;

  const short* xsrc = Abf + ((size_t)(bx * 64 + (tid >> 2))) * 256 + (tid & 3) * 8;
  const short* wsrc = WoT + ((size_t)(tid >> 2)) * 256 + (tid & 3) * 8;
  short* xdst0 = &Xs[0][tid * 8];
  short* xdst1 = &Xs[1][tid * 8];
  short* wdst0 = &Ws[0][tid * 8];
  short* wdst1 = &Ws[1][tid * 8];

  bf16x8 xr, wr[4];
  xr = *(const bf16x8*)xsrc;
#pragma unroll
  for (int p = 0; p < 4; ++p) wr[p] = *(const bf16x8*)(wsrc + (size_t)p * 64 * 256);
  *(bf16x8*)xdst0 = xr;
#pragma unroll
  for (int p = 0; p < 4; ++p) *(bf16x8*)(wdst0 + p * 2048) = wr[p];
  __syncthreads();

  f32x4 acc[4][4];
#pragma unroll
  for (int i = 0; i < 4; ++i)
#pragma unroll
    for (int mh = 0; mh < 4; ++mh) acc[i][mh] = f32x4{0.f, 0.f, 0.f, 0.f};

  for (int ks = 0; ks < 8; ++ks) {
    const int cur = ks & 1;
    if (ks < 7) {
      xr = *(const bf16x8*)(xsrc + (ks + 1) * 32);
#pragma unroll
      for (int p = 0; p < 4; ++p)
        wr[p] = *(const bf16x8*)(wsrc + (size_t)p * 64 * 256 + (ks + 1) * 32);
    }
    bf16x8 wf[4], xf[4];
#pragma unroll
    for (int i = 0; i < 4; ++i)
      wf[i] = *(const bf16x8*)&Ws[cur][((nt0 + i) * 16 + l15) * 32 + l4 * 8];
#pragma unroll
    for (int mh = 0; mh < 4; ++mh)
      xf[mh] = *(const bf16x8*)&Xs[cur][(mh * 16 + l15) * 32 + l4 * 8];
#pragma unroll
    for (int i = 0; i < 4; ++i)
#pragma unroll
      for (int mh = 0; mh < 4; ++mh)
        acc[i][mh] = mfma16(wf[i], xf[mh], acc[i][mh]);
    if (ks < 7) {
      short* xd = (cur ? xdst0 : xdst1);
      short* wd = (cur ? wdst0 : wdst1);
      *(bf16x8*)xd = xr;
#pragma unroll
      for (int p = 0; p < 4; ++p) *(bf16x8*)(wd + p * 2048) = wr[p];
    }
    __syncthreads();
  }

#pragma unroll
  for (int i = 0; i < 4; ++i) {
    const int n0 = (nt0 + i) * 16 + l4 * 4;
    float4 bi = *(const float4*)(bo + n0);
#pragma unroll
    for (int mh = 0; mh < 4; ++mh) {
      const int m = bx * 64 + mh * 16 + l15;
      float4 r;
      r.x = acc[i][mh][0] + bi.x;
      r.y = acc[i][mh][1] + bi.y;
      r.z = acc[i][mh][2] + bi.z;
      r.w = acc[i][mh][3] + bi.w;
      *(float4*)(out + (size_t)m * 256 + n0) = r;
    }
  }
}

// ---------------------------------------------------------------------------
// Flash attention v13: R8 structure (no split, no reg cap, natural 2
// blocks/CU) + SINGLE barrier per tile via K double-buffer + V TRIPLE-buffer.
// R8 needed 2 barriers because PV(t-1) reads Vs[prv] while write V(t+1)
// targets Vs[prv] (mod-2 collision from V's one-tile lag). With V mod-3:
//   iter t: reads Ks[t&1], Vs[(t-1)%3]; writes Ks[(t+1)&1], Vs[t%3]
// all four distinct; cross-iteration hazards separated by the one barrier.
// LDS 80 KB -> still 2 blocks/CU. Burst{QK(t) || PV(t-1) || lsum} -> exp ->
// writes -> barrier.
// ---------------------------------------------------------------------------
__global__ __launch_bounds__(256) void attn_kernel13(
    const short* __restrict__ Q, const short* __restrict__ K,
    const short* __restrict__ VT, short* __restrict__ Abf) {
  const int lin = blockIdx.x;   // 512
  const int bh = lin & 31;      // same-bh blocks land on same XCD
  const int qt = lin >> 5;      // 0..15
  const int tid = threadIdx.x, wid = tid >> 6, lane = tid & 63;
  const int q31 = lane & 31, h = lane >> 5;
  constexpr int NT = S / 64;  // 32

  __shared__ short Ks[2][64 * 128];  // [kv][d], swizzled, pitch 128
  __shared__ short Vs[3][64 * 128];  // [d][kv], swizzled, pitch 128

  const short* Kg = K + (size_t)bh * S * HD;
  const short* Vg = VT + (size_t)bh * HD * S;
  const int qrow = qt * 128 + wid * 32;

  const short* Qg = Q + ((size_t)bh * S + qrow + q31) * HD + h * 8;
  bf16x8 qf[4];
#pragma unroll
  for (int ds = 0; ds < 4; ++ds) qf[ds] = *(const bf16x8*)(Qg + ds * 16);

  bf16x8 ones;
#pragma unroll
  for (int i = 0; i < 8; ++i) ones[i] = (short)0x3F80;

  const int srow = tid >> 2;
  const int scol = (tid & 3) * 16;
  const int swz = (srow & 15) * 8;
  const int c0 = scol ^ swz;
  const int c1 = (scol + 8) ^ swz;

  const int fs = (lane & 15) * 8;
  int kcol[4];
#pragma unroll
  for (int ds = 0; ds < 4; ++ds) kcol[ds] = (ds * 16 + h * 8) ^ fs;

  // ---- prologue: stage K(0) -> Ks[0]; issue loads K(1), V(0); barrier ----
  bf16x8 kr0, kr1, vr0, vr1;
  kr0 = *(const bf16x8*)(Kg + (size_t)srow * HD + scol);
  kr1 = *(const bf16x8*)(Kg + (size_t)srow * HD + scol + 8);
  *(bf16x8*)&Ks[0][srow * 128 + c0] = kr0;
  *(bf16x8*)&Ks[0][srow * 128 + c1] = kr1;
  {
    const short* Kn = Kg + (size_t)64 * HD;
    kr0 = *(const bf16x8*)(Kn + (size_t)srow * HD + scol);
    kr1 = *(const bf16x8*)(Kn + (size_t)srow * HD + scol + 8);
    vr0 = *(const bf16x8*)(Vg + (size_t)srow * S + scol);
    vr1 = *(const bf16x8*)(Vg + (size_t)srow * S + scol + 8);
  }
  __syncthreads();

  f32x16 o0, o1, lsum;
#pragma unroll
  for (int i = 0; i < 16; ++i) { o0[i] = 0.f; o1[i] = 0.f; lsum[i] = 0.f; }
  bf16x8 pB[4];

#define EXPPACK(S0, S1)                                               \
  {                                                                   \
    _Pragma("unroll") for (int win = 0; win < 2; ++win) {             \
      const f32x16& sc = win ? (S1) : (S0);                           \
      float p[16];                                                    \
      _Pragma("unroll") for (int r = 0; r < 16; ++r)                  \
          p[r] = exp2a(sc[r]);                                        \
      unsigned w[8];                                                  \
      _Pragma("unroll") for (int i = 0; i < 8; ++i)                   \
          w[i] = cvtpk(p[2 * i], p[2 * i + 1]);                       \
      unsigned x0 = w[0], y0 = w[2], x1 = w[1], y1 = w[3];            \
      unsigned x2 = w[4], y2 = w[6], x3 = w[5], y3 = w[7];            \
      asm("v_permlane32_swap_b32 %0, %1" : "+v"(x0), "+v"(y0));       \
      asm("v_permlane32_swap_b32 %0, %1" : "+v"(x1), "+v"(y1));       \
      asm("v_permlane32_swap_b32 %0, %1" : "+v"(x2), "+v"(y2));       \
      asm("v_permlane32_swap_b32 %0, %1" : "+v"(x3), "+v"(y3));       \
      uint4v u0 = {x0, x1, y0, y1};                                   \
      uint4v u1 = {x2, x3, y2, y3};                                   \
      __builtin_memcpy(&pB[win * 2 + 0], &u0, 16);                    \
      __builtin_memcpy(&pB[win * 2 + 1], &u1, 16);                    \
    }                                                                 \
  }

  // ---- peeled iteration 0: QK(0); exp(0); write K(1)->Ks[1], V(0)->Vs[0];
  //      single barrier ----
  {
    f32x16 sc0, sc1;
#pragma unroll
    for (int i = 0; i < 16; ++i) { sc0[i] = 0.f; sc1[i] = 0.f; }
    __builtin_amdgcn_s_setprio(1);
#pragma unroll
    for (int ds = 0; ds < 4; ++ds) {
      bf16x8 k0 = *(const bf16x8*)&Ks[0][(q31)*128 + kcol[ds]];
      bf16x8 k1 = *(const bf16x8*)&Ks[0][(32 + q31) * 128 + kcol[ds]];
      sc0 = mfma32(k0, qf[ds], sc0);
      sc1 = mfma32(k1, qf[ds], sc1);
    }
    __builtin_amdgcn_s_setprio(0);
    EXPPACK(sc0, sc1);
    *(bf16x8*)&Ks[1][srow * 128 + c0] = kr0;
    *(bf16x8*)&Ks[1][srow * 128 + c1] = kr1;
    *(bf16x8*)&Vs[0][srow * 128 + c0] = vr0;
    *(bf16x8*)&Vs[0][srow * 128 + c1] = vr1;
    __syncthreads();
  }

  // ---- main loop t = 1 .. NT-1 ----
  // invariant at top: Ks[t&1] = K(t); Vs[(t-1)%3] = V(t-1); pB = P(t-1)
  int vrd = 0;  // (t-1)%3
  int vwr = 1;  // t%3
  for (int kt = 1; kt < NT; ++kt) {
    if (kt + 1 < NT) {
      const short* Kn = Kg + (size_t)(kt + 1) * 64 * HD;
      kr0 = *(const bf16x8*)(Kn + (size_t)srow * HD + scol);
      kr1 = *(const bf16x8*)(Kn + (size_t)srow * HD + scol + 8);
    }
    vr0 = *(const bf16x8*)(Vg + (size_t)srow * S + kt * 64 + scol);
    vr1 = *(const bf16x8*)(Vg + (size_t)srow * S + kt * 64 + scol + 8);

    f32x16 sc0, sc1;
#pragma unroll
    for (int i = 0; i < 16; ++i) { sc0[i] = 0.f; sc1[i] = 0.f; }

    const short* kb = &Ks[kt & 1][0];
    const short* vb = &Vs[vrd][0];
    __builtin_amdgcn_s_setprio(1);
#pragma unroll
    for (int ds = 0; ds < 4; ++ds) {
      bf16x8 k0 = *(const bf16x8*)&kb[(q31)*128 + kcol[ds]];
      bf16x8 k1 = *(const bf16x8*)&kb[(32 + q31) * 128 + kcol[ds]];
      sc0 = mfma32(k0, qf[ds], sc0);
      sc1 = mfma32(k1, qf[ds], sc1);
      bf16x8 v0 = *(const bf16x8*)&vb[(q31)*128 + kcol[ds]];
      bf16x8 v1 = *(const bf16x8*)&vb[(32 + q31) * 128 + kcol[ds]];
      o0 = mfma32(v0, pB[ds], o0);
      o1 = mfma32(v1, pB[ds], o1);
      lsum = mfma32(ones, pB[ds], lsum);
    }
    __builtin_amdgcn_s_setprio(0);

    EXPPACK(sc0, sc1);

    if (kt + 1 < NT) {
      short* kw = &Ks[(kt + 1) & 1][0];
      *(bf16x8*)&kw[srow * 128 + c0] = kr0;
      *(bf16x8*)&kw[srow * 128 + c1] = kr1;
    }
    {
      short* vw = &Vs[vwr][0];
      *(bf16x8*)&vw[srow * 128 + c0] = vr0;
      *(bf16x8*)&vw[srow * 128 + c1] = vr1;
    }
    __syncthreads();  // single barrier: publishes K(t+1), V(t)

    vrd = vwr;
    vwr = (vwr == 2) ? 0 : vwr + 1;
  }

  // ---- epilogue: PV(NT-1) from Vs[(NT-1)%3]; pB = P(NT-1) ----
  {
    const short* vb = &Vs[vrd][0];
    __builtin_amdgcn_s_setprio(1);
#pragma unroll
    for (int ds = 0; ds < 4; ++ds) {
      bf16x8 v0 = *(const bf16x8*)&vb[(q31)*128 + kcol[ds]];
      bf16x8 v1 = *(const bf16x8*)&vb[(32 + q31) * 128 + kcol[ds]];
      o0 = mfma32(v0, pB[ds], o0);
      o1 = mfma32(v1, pB[ds], o1);
      lsum = mfma32(ones, pB[ds], lsum);
    }
    __builtin_amdgcn_s_setprio(0);
  }
#undef EXPPACK

  // lsum[0] = full column sum for this lane's q
  const float inv = 1.0f / lsum[0];
  const int b = bh >> 2, hh = bh & 3;
  short* ap = Abf + ((size_t)b * S + qrow + q31) * 256 + hh * 64;
#pragma unroll
  for (int dt = 0; dt < 2; ++dt) {
    const f32x16& o = dt ? o1 : o0;
#pragma unroll
    for (int g = 0; g < 4; ++g) {
      const int d0 = dt * 32 + 8 * g + 4 * h;
      bf16x4 r = pk4(o[4 * g + 0] * inv, o[4 * g + 1] * inv,
                     o[4 * g + 2] * inv, o[4 * g + 3] * inv);
      *(bf16x4*)(ap + d0) = r;
    }
  }
}

}  // namespace

extern "C" void kernel_launch(void* const* d_in, const int* in_sizes, int n_in,
                              void* d_out, int out_size, void* d_ws, size_t ws_size,
                              hipStream_t stream) {
  const float* x  = (const float*)d_in[0];
  const float* Wq = (const float*)d_in[1];
  const float* bq = (const float*)d_in[2];
  const float* Wk = (const float*)d_in[3];
  const float* bk = (const float*)d_in[4];
  const float* Wv = (const float*)d_in[5];
  const float* bv = (const float*)d_in[6];
  const float* Wo = (const float*)d_in[7];
  const float* bo = (const float*)d_in[8];
  float* out = (float*)d_out;

  const size_t per = (size_t)M * D;
  short* WqT = (short*)d_ws;
  short* WkT = WqT + 256 * 256;
  short* WvT = WkT + 256 * 256;
  short* WoT = WvT + 256 * 256;
  short* Qbf = WoT + 256 * 256;
  short* Kbf = Qbf + per;
  short* Vt  = Kbf + per;          // [bh][d][s]
  short* Abf = Vt + per;

  prep_w_kernel<<<64, 256, 0, stream>>>(Wq, Wk, Wv, Wo, WqT, WkT, WvT, WoT);
  gemm_qkv_kernel<<<dim3(256, 3), 256, 0, stream>>>(x, WqT, WkT, WvT, bq, bk, bv,
                                                    Qbf, Kbf, Vt);
  attn_kernel13<<<512, 256, 0, stream>>>(Qbf, Kbf, Vt, Abf);
  gemm_out_kernel<<<256, 256, 0, stream>>>(Abf, WoT, bo, out);
}

// Round 15
// 88.167 us; speedup vs baseline: 2.7865x; 1.0071x over previous
//
#include <hip/hip_runtime.h>
#include <hip/hip_bf16.h>

namespace {

constexpr int B_ = 8, S = 2048, D = 256, H = 4, HD = 64;
constexpr int M = B_ * S;  // 16384

typedef __attribute__((ext_vector_type(8))) short bf16x8;
typedef __attribute__((ext_vector_type(4))) short bf16x4;
typedef __attribute__((ext_vector_type(4))) float f32x4;
typedef __attribute__((ext_vector_type(16))) float f32x16;
typedef __attribute__((ext_vector_type(4))) unsigned uint4v;

__device__ inline short f2bf(float x) {
  __hip_bfloat16 h = __float2bfloat16(x);
  short s;
  __builtin_memcpy(&s, &h, 2);
  return s;
}

__device__ inline f32x4 mfma16(bf16x8 a, bf16x8 b, f32x4 c) {
  return __builtin_amdgcn_mfma_f32_16x16x32_bf16(a, b, c, 0, 0, 0);
}
__device__ inline f32x16 mfma32(bf16x8 a, bf16x8 b, f32x16 c) {
  return __builtin_amdgcn_mfma_f32_32x32x16_bf16(a, b, c, 0, 0, 0);
}

// raw 2^x
__device__ inline float exp2a(float x) {
  float r;
  asm("v_exp_f32 %0, %1" : "=v"(r) : "v"(x));
  return r;
}

// HW packed f32x2 -> bf16x2 (RNE)
__device__ inline unsigned cvtpk(float lo, float hi) {
  unsigned r;
  asm("v_cvt_pk_bf16_f32 %0, %1, %2" : "=v"(r) : "v"(lo), "v"(hi));
  return r;
}

__device__ inline bf16x4 pk4(float a, float b, float c, float d) {
  unsigned lo = cvtpk(a, b), hi = cvtpk(c, d);
  uint2 u{lo, hi};
  bf16x4 r;
  __builtin_memcpy(&r, &u, 8);
  return r;
}

// load 8 fp32, convert to bf16x8
__device__ inline bf16x8 ld_cvt8(const float* p) {
  float4 a = *(const float4*)p;
  float4 b = *(const float4*)(p + 4);
  uint4v u = {cvtpk(a.x, a.y), cvtpk(a.z, a.w), cvtpk(b.x, b.y), cvtpk(b.z, b.w)};
  bf16x8 r;
  __builtin_memcpy(&r, &u, 16);
  return r;
}

// ---------------------------------------------------------------------------
// Prep: 64 blocks transpose W{q,k,v,o} fp32[k][n] -> bf16 Wt[n][k].
// ---------------------------------------------------------------------------
__global__ __launch_bounds__(256) void prep_w_kernel(
    const float* __restrict__ Wq, const float* __restrict__ Wk,
    const float* __restrict__ Wv, const float* __restrict__ Wo,
    short* __restrict__ WqT, short* __restrict__ WkT,
    short* __restrict__ WvT, short* __restrict__ WoT) {
  const int blk = blockIdx.x, t = threadIdx.x;
  const int wq = blk >> 4, n0 = (blk & 15) * 16;
  const float* W = wq == 0 ? Wq : wq == 1 ? Wk : wq == 2 ? Wv : Wo;
  short* Wt = wq == 0 ? WqT : wq == 1 ? WkT : wq == 2 ? WvT : WoT;
#pragma unroll
  for (int j4 = 0; j4 < 4; ++j4) {
    float4 v = *(const float4*)(W + (size_t)t * 256 + n0 + j4 * 4);
    Wt[(n0 + j4 * 4 + 0) * 256 + t] = f2bf(v.x);
    Wt[(n0 + j4 * 4 + 1) * 256 + t] = f2bf(v.y);
    Wt[(n0 + j4 * 4 + 2) * 256 + t] = f2bf(v.z);
    Wt[(n0 + j4 * 4 + 3) * 256 + t] = f2bf(v.w);
  }
}

// ---------------------------------------------------------------------------
// QKV GEMM: x staged fp32 -> cvt_pk -> LDS. Q scale folds 1/8*log2e;
// V written [bh][d][s] via operand swap.
// ---------------------------------------------------------------------------
__global__ __launch_bounds__(256) void gemm_qkv_kernel(
    const float* __restrict__ x,
    const short* __restrict__ WqT, const short* __restrict__ WkT,
    const short* __restrict__ WvT,
    const float* __restrict__ bq, const float* __restrict__ bk,
    const float* __restrict__ bv,
    short* __restrict__ Qo, short* __restrict__ Ko, short* __restrict__ Vt) {
  const int bx = blockIdx.x;
  const int which = blockIdx.y;
  const short* Wt = which == 0 ? WqT : which == 1 ? WkT : WvT;
  const float* bias = which == 0 ? bq : which == 1 ? bk : bv;

  __shared__ short Xs[2][64 * 32];
  __shared__ short Ws[2][256 * 32];

  const int tid = threadIdx.x;
  const int wid = tid >> 6, lane = tid & 63;
  const int l15 = lane & 15, l4 = lane >> 4;
  const int nt0 = wid * 4;

  const float* xsrc = x + ((size_t)(bx * 64 + (tid >> 2))) * 256 + (tid & 3) * 8;
  const short* wsrc = Wt + ((size_t)(tid >> 2)) * 256 + (tid & 3) * 8;
  short* xdst0 = &Xs[0][tid * 8];
  short* xdst1 = &Xs[1][tid * 8];
  short* wdst0 = &Ws[0][tid * 8];
  short* wdst1 = &Ws[1][tid * 8];

  bf16x8 xr, wr[4];
  xr = ld_cvt8(xsrc);
#pragma unroll
  for (int p = 0; p < 4; ++p) wr[p] = *(const bf16x8*)(wsrc + (size_t)p * 64 * 256);
  *(bf16x8*)xdst0 = xr;
#pragma unroll
  for (int p = 0; p < 4; ++p) *(bf16x8*)(wdst0 + p * 2048) = wr[p];
  __syncthreads();

  f32x4 acc[4][4];
#pragma unroll
  for (int i = 0; i < 4; ++i)
#pragma unroll
    for (int mh = 0; mh < 4; ++mh) acc[i][mh] = f32x4{0.f, 0.f, 0.f, 0.f};

  for (int ks = 0; ks < 8; ++ks) {
    const int cur = ks & 1;
    if (ks < 7) {
      xr = ld_cvt8(xsrc + (ks + 1) * 32);
#pragma unroll
      for (int p = 0; p < 4; ++p)
        wr[p] = *(const bf16x8*)(wsrc + (size_t)p * 64 * 256 + (ks + 1) * 32);
    }
    bf16x8 wf[4], xf[4];
#pragma unroll
    for (int i = 0; i < 4; ++i)
      wf[i] = *(const bf16x8*)&Ws[cur][((nt0 + i) * 16 + l15) * 32 + l4 * 8];
#pragma unroll
    for (int mh = 0; mh < 4; ++mh)
      xf[mh] = *(const bf16x8*)&Xs[cur][(mh * 16 + l15) * 32 + l4 * 8];
    if (which == 2) {
#pragma unroll
      for (int i = 0; i < 4; ++i)
#pragma unroll
        for (int mh = 0; mh < 4; ++mh)
          acc[i][mh] = mfma16(xf[mh], wf[i], acc[i][mh]);  // D[m][n]
    } else {
#pragma unroll
      for (int i = 0; i < 4; ++i)
#pragma unroll
        for (int mh = 0; mh < 4; ++mh)
          acc[i][mh] = mfma16(wf[i], xf[mh], acc[i][mh]);  // D[n][m]
    }
    if (ks < 7) {
      short* xd = (cur ? xdst0 : xdst1);
      short* wd = (cur ? wdst0 : wdst1);
      *(bf16x8*)xd = xr;
#pragma unroll
      for (int p = 0; p < 4; ++p) *(bf16x8*)(wd + p * 2048) = wr[p];
    }
    __syncthreads();
  }

  if (which == 2) {
    const int m0 = bx * 64 + l4 * 4;
#pragma unroll
    for (int i = 0; i < 4; ++i) {
      const int n = (nt0 + i) * 16 + l15;
      const float bi = bias[n];
      const int h = n >> 6, d = n & 63;
#pragma unroll
      for (int mh = 0; mh < 4; ++mh) {
        const int m = m0 + mh * 16;
        const int bb = m >> 11, s0 = m & 2047;
        bf16x4 r = pk4(acc[i][mh][0] + bi, acc[i][mh][1] + bi,
                       acc[i][mh][2] + bi, acc[i][mh][3] + bi);
        *(bf16x4*)(Vt + (((size_t)bb * H + h) * HD + d) * S + s0) = r;
      }
    }
  } else {
    const float scale = which == 0 ? 0.18033688011112042f : 1.0f;  // 1/8*log2e
    short* outp = which == 0 ? Qo : Ko;
#pragma unroll
    for (int i = 0; i < 4; ++i) {
      const int n0 = (nt0 + i) * 16 + l4 * 4;
      float4 bi = *(const float4*)(bias + n0);
      const int h = n0 >> 6, d0 = n0 & 63;
#pragma unroll
      for (int mh = 0; mh < 4; ++mh) {
        const int m = bx * 64 + mh * 16 + l15;
        const int bb = m >> 11, s = m & 2047;
        bf16x4 r = pk4((acc[i][mh][0] + bi.x) * scale, (acc[i][mh][1] + bi.y) * scale,
                       (acc[i][mh][2] + bi.z) * scale, (acc[i][mh][3] + bi.w) * scale);
        *(bf16x4*)(outp + (((size_t)bb * H + h) * S + s) * HD + d0) = r;
      }
    }
  }
}

// ---------------------------------------------------------------------------
// Out projection GEMM (bf16 A in, fp32 out)
// ---------------------------------------------------------------------------
__global__ __launch_bounds__(256) void gemm_out_kernel(
    const short* __restrict__ Abf, const short* __restrict__ WoT,
    const float* __restrict__ bo, float* __restrict__ out) {
  const int bx = blockIdx.x;
  __shared__ short Xs[2][64 * 32];
  __shared__ short Ws[2][256 * 32];

  const int tid = threadIdx.x;
  const int wid = tid >> 6, lane = tid & 63;
  const int l15 = lane & 15, l4 = lane >> 4;
  const int nt0 = wid * 4;

  const short* xsrc = Abf + ((size_t)(bx * 64 + (tid >> 2))) * 256 + (tid & 3) * 8;
  const short* wsrc = WoT + ((size_t)(tid >> 2)) * 256 + (tid & 3) * 8;
  short* xdst0 = &Xs[0][tid * 8];
  short* xdst1 = &Xs[1][tid * 8];
  short* wdst0 = &Ws[0][tid * 8];
  short* wdst1 = &Ws[1][tid * 8];

  bf16x8 xr, wr[4];
  xr = *(const bf16x8*)xsrc;
#pragma unroll
  for (int p = 0; p < 4; ++p) wr[p] = *(const bf16x8*)(wsrc + (size_t)p * 64 * 256);
  *(bf16x8*)xdst0 = xr;
#pragma unroll
  for (int p = 0; p < 4; ++p) *(bf16x8*)(wdst0 + p * 2048) = wr[p];
  __syncthreads();

  f32x4 acc[4][4];
#pragma unroll
  for (int i = 0; i < 4; ++i)
#pragma unroll
    for (int mh = 0; mh < 4; ++mh) acc[i][mh] = f32x4{0.f, 0.f, 0.f, 0.f};

  for (int ks = 0; ks < 8; ++ks) {
    const int cur = ks & 1;
    if (ks < 7) {
      xr = *(const bf16x8*)(xsrc + (ks + 1) * 32);
#pragma unroll
      for (int p = 0; p < 4; ++p)
        wr[p] = *(const bf16x8*)(wsrc + (size_t)p * 64 * 256 + (ks + 1) * 32);
    }
    bf16x8 wf[4], xf[4];
#pragma unroll
    for (int i = 0; i < 4; ++i)
      wf[i] = *(const bf16x8*)&Ws[cur][((nt0 + i) * 16 + l15) * 32 + l4 * 8];
#pragma unroll
    for (int mh = 0; mh < 4; ++mh)
      xf[mh] = *(const bf16x8*)&Xs[cur][(mh * 16 + l15) * 32 + l4 * 8];
#pragma unroll
    for (int i = 0; i < 4; ++i)
#pragma unroll
      for (int mh = 0; mh < 4; ++mh)
        acc[i][mh] = mfma16(wf[i], xf[mh], acc[i][mh]);
    if (ks < 7) {
      short* xd = (cur ? xdst0 : xdst1);
      short* wd = (cur ? wdst0 : wdst1);
      *(bf16x8*)xd = xr;
#pragma unroll
      for (int p = 0; p < 4; ++p) *(bf16x8*)(wd + p * 2048) = wr[p];
    }
    __syncthreads();
  }

#pragma unroll
  for (int i = 0; i < 4; ++i) {
    const int n0 = (nt0 + i) * 16 + l4 * 4;
    float4 bi = *(const float4*)(bo + n0);
#pragma unroll
    for (int mh = 0; mh < 4; ++mh) {
      const int m = bx * 64 + mh * 16 + l15;
      float4 r;
      r.x = acc[i][mh][0] + bi.x;
      r.y = acc[i][mh][1] + bi.y;
      r.z = acc[i][mh][2] + bi.z;
      r.w = acc[i][mh][3] + bi.w;
      *(float4*)(out + (size_t)m * 256 + n0) = r;
    }
  }
}

// ---------------------------------------------------------------------------
// Flash attention v13: R8 structure (no split, no reg cap, natural 2
// blocks/CU) + SINGLE barrier per tile via K double-buffer + V TRIPLE-buffer.
// R8 needed 2 barriers because PV(t-1) reads Vs[prv] while write V(t+1)
// targets Vs[prv] (mod-2 collision from V's one-tile lag). With V mod-3:
//   iter t: reads Ks[t&1], Vs[(t-1)%3]; writes Ks[(t+1)&1], Vs[t%3]
// all four distinct; cross-iteration hazards separated by the one barrier.
// LDS 80 KB -> still 2 blocks/CU. Burst{QK(t) || PV(t-1) || lsum} -> exp ->
// writes -> barrier.
// ---------------------------------------------------------------------------
__global__ __launch_bounds__(256) void attn_kernel13(
    const short* __restrict__ Q, const short* __restrict__ K,
    const short* __restrict__ VT, short* __restrict__ Abf) {
  const int lin = blockIdx.x;   // 512
  const int bh = lin & 31;      // same-bh blocks land on same XCD
  const int qt = lin >> 5;      // 0..15
  const int tid = threadIdx.x, wid = tid >> 6, lane = tid & 63;
  const int q31 = lane & 31, h = lane >> 5;
  constexpr int NT = S / 64;  // 32

  __shared__ short Ks[2][64 * 128];  // [kv][d], swizzled, pitch 128
  __shared__ short Vs[3][64 * 128];  // [d][kv], swizzled, pitch 128

  const short* Kg = K + (size_t)bh * S * HD;
  const short* Vg = VT + (size_t)bh * HD * S;
  const int qrow = qt * 128 + wid * 32;

  const short* Qg = Q + ((size_t)bh * S + qrow + q31) * HD + h * 8;
  bf16x8 qf[4];
#pragma unroll
  for (int ds = 0; ds < 4; ++ds) qf[ds] = *(const bf16x8*)(Qg + ds * 16);

  bf16x8 ones;
#pragma unroll
  for (int i = 0; i < 8; ++i) ones[i] = (short)0x3F80;

  const int srow = tid >> 2;
  const int scol = (tid & 3) * 16;
  const int swz = (srow & 15) * 8;
  const int c0 = scol ^ swz;
  const int c1 = (scol + 8) ^ swz;

  const int fs = (lane & 15) * 8;
  int kcol[4];
#pragma unroll
  for (int ds = 0; ds < 4; ++ds) kcol[ds] = (ds * 16 + h * 8) ^ fs;

  // ---- prologue: stage K(0) -> Ks[0]; issue loads K(1), V(0); barrier ----
  bf16x8 kr0, kr1, vr0, vr1;
  kr0 = *(const bf16x8*)(Kg + (size_t)srow * HD + scol);
  kr1 = *(const bf16x8*)(Kg + (size_t)srow * HD + scol + 8);
  *(bf16x8*)&Ks[0][srow * 128 + c0] = kr0;
  *(bf16x8*)&Ks[0][srow * 128 + c1] = kr1;
  {
    const short* Kn = Kg + (size_t)64 * HD;
    kr0 = *(const bf16x8*)(Kn + (size_t)srow * HD + scol);
    kr1 = *(const bf16x8*)(Kn + (size_t)srow * HD + scol + 8);
    vr0 = *(const bf16x8*)(Vg + (size_t)srow * S + scol);
    vr1 = *(const bf16x8*)(Vg + (size_t)srow * S + scol + 8);
  }
  __syncthreads();

  f32x16 o0, o1, lsum;
#pragma unroll
  for (int i = 0; i < 16; ++i) { o0[i] = 0.f; o1[i] = 0.f; lsum[i] = 0.f; }
  bf16x8 pB[4];

#define EXPPACK(S0, S1)                                               \
  {                                                                   \
    _Pragma("unroll") for (int win = 0; win < 2; ++win) {             \
      const f32x16& sc = win ? (S1) : (S0);                           \
      float p[16];                                                    \
      _Pragma("unroll") for (int r = 0; r < 16; ++r)                  \
          p[r] = exp2a(sc[r]);                                        \
      unsigned w[8];                                                  \
      _Pragma("unroll") for (int i = 0; i < 8; ++i)                   \
          w[i] = cvtpk(p[2 * i], p[2 * i + 1]);                       \
      unsigned x0 = w[0], y0 = w[2], x1 = w[1], y1 = w[3];            \
      unsigned x2 = w[4], y2 = w[6], x3 = w[5], y3 = w[7];            \
      asm("v_permlane32_swap_b32 %0, %1" : "+v"(x0), "+v"(y0));       \
      asm("v_permlane32_swap_b32 %0, %1" : "+v"(x1), "+v"(y1));       \
      asm("v_permlane32_swap_b32 %0, %1" : "+v"(x2), "+v"(y2));       \
      asm("v_permlane32_swap_b32 %0, %1" : "+v"(x3), "+v"(y3));       \
      uint4v u0 = {x0, x1, y0, y1};                                   \
      uint4v u1 = {x2, x3, y2, y3};                                   \
      __builtin_memcpy(&pB[win * 2 + 0], &u0, 16);                    \
      __builtin_memcpy(&pB[win * 2 + 1], &u1, 16);                    \
    }                                                                 \
  }

  // ---- peeled iteration 0: QK(0); exp(0); write K(1)->Ks[1], V(0)->Vs[0];
  //      single barrier ----
  {
    f32x16 sc0, sc1;
#pragma unroll
    for (int i = 0; i < 16; ++i) { sc0[i] = 0.f; sc1[i] = 0.f; }
    __builtin_amdgcn_s_setprio(1);
#pragma unroll
    for (int ds = 0; ds < 4; ++ds) {
      bf16x8 k0 = *(const bf16x8*)&Ks[0][(q31)*128 + kcol[ds]];
      bf16x8 k1 = *(const bf16x8*)&Ks[0][(32 + q31) * 128 + kcol[ds]];
      sc0 = mfma32(k0, qf[ds], sc0);
      sc1 = mfma32(k1, qf[ds], sc1);
    }
    __builtin_amdgcn_s_setprio(0);
    EXPPACK(sc0, sc1);
    *(bf16x8*)&Ks[1][srow * 128 + c0] = kr0;
    *(bf16x8*)&Ks[1][srow * 128 + c1] = kr1;
    *(bf16x8*)&Vs[0][srow * 128 + c0] = vr0;
    *(bf16x8*)&Vs[0][srow * 128 + c1] = vr1;
    __syncthreads();
  }

  // ---- main loop t = 1 .. NT-1 ----
  // invariant at top: Ks[t&1] = K(t); Vs[(t-1)%3] = V(t-1); pB = P(t-1)
  int vrd = 0;  // (t-1)%3
  int vwr = 1;  // t%3
  for (int kt = 1; kt < NT; ++kt) {
    if (kt + 1 < NT) {
      const short* Kn = Kg + (size_t)(kt + 1) * 64 * HD;
      kr0 = *(const bf16x8*)(Kn + (size_t)srow * HD + scol);
      kr1 = *(const bf16x8*)(Kn + (size_t)srow * HD + scol + 8);
    }
    vr0 = *(const bf16x8*)(Vg + (size_t)srow * S + kt * 64 + scol);
    vr1 = *(const bf16x8*)(Vg + (size_t)srow * S + kt * 64 + scol + 8);

    f32x16 sc0, sc1;
#pragma unroll
    for (int i = 0; i < 16; ++i) { sc0[i] = 0.f; sc1[i] = 0.f; }

    const short* kb = &Ks[kt & 1][0];
    const short* vb = &Vs[vrd][0];
    __builtin_amdgcn_s_setprio(1);
#pragma unroll
    for (int ds = 0; ds < 4; ++ds) {
      bf16x8 k0 = *(const bf16x8*)&kb[(q31)*128 + kcol[ds]];
      bf16x8 k1 = *(const bf16x8*)&kb[(32 + q31) * 128 + kcol[ds]];
      sc0 = mfma32(k0, qf[ds], sc0);
      sc1 = mfma32(k1, qf[ds], sc1);
      bf16x8 v0 = *(const bf16x8*)&vb[(q31)*128 + kcol[ds]];
      bf16x8 v1 = *(const bf16x8*)&vb[(32 + q31) * 128 + kcol[ds]];
      o0 = mfma32(v0, pB[ds], o0);
      o1 = mfma32(v1, pB[ds], o1);
      lsum = mfma32(ones, pB[ds], lsum);
    }
    __builtin_amdgcn_s_setprio(0);

    EXPPACK(sc0, sc1);

    if (kt + 1 < NT) {
      short* kw = &Ks[(kt + 1) & 1][0];
      *(bf16x8*)&kw[srow * 128 + c0] = kr0;
      *(bf16x8*)&kw[srow * 128 + c1] = kr1;
    }
    {
      short* vw = &Vs[vwr][0];
      *(bf16x8*)&vw[srow * 128 + c0] = vr0;
      *(bf16x8*)&vw[srow * 128 + c1] = vr1;
    }
    __syncthreads();  // single barrier: publishes K(t+1), V(t)

    vrd = vwr;
    vwr = (vwr == 2) ? 0 : vwr + 1;
  }

  // ---- epilogue: PV(NT-1) from Vs[(NT-1)%3]; pB = P(NT-1) ----
  {
    const short* vb = &Vs[vrd][0];
    __builtin_amdgcn_s_setprio(1);
#pragma unroll
    for (int ds = 0; ds < 4; ++ds) {
      bf16x8 v0 = *(const bf16x8*)&vb[(q31)*128 + kcol[ds]];
      bf16x8 v1 = *(const bf16x8*)&vb[(32 + q31) * 128 + kcol[ds]];
      o0 = mfma32(v0, pB[ds], o0);
      o1 = mfma32(v1, pB[ds], o1);
      lsum = mfma32(ones, pB[ds], lsum);
    }
    __builtin_amdgcn_s_setprio(0);
  }
#undef EXPPACK

  // lsum[0] = full column sum for this lane's q
  const float inv = 1.0f / lsum[0];
  const int b = bh >> 2, hh = bh & 3;
  short* ap = Abf + ((size_t)b * S + qrow + q31) * 256 + hh * 64;
#pragma unroll
  for (int dt = 0; dt < 2; ++dt) {
    const f32x16& o = dt ? o1 : o0;
#pragma unroll
    for (int g = 0; g < 4; ++g) {
      const int d0 = dt * 32 + 8 * g + 4 * h;
      bf16x4 r = pk4(o[4 * g + 0] * inv, o[4 * g + 1] * inv,
                     o[4 * g + 2] * inv, o[4 * g + 3] * inv);
      *(bf16x4*)(ap + d0) = r;
    }
  }
}

}  // namespace

extern "C" void kernel_launch(void* const* d_in, const int* in_sizes, int n_in,
                              void* d_out, int out_size, void* d_ws, size_t ws_size,
                              hipStream_t stream) {
  const float* x  = (const float*)d_in[0];
  const float* Wq = (const float*)d_in[1];
  const float* bq = (const float*)d_in[2];
  const float* Wk = (const float*)d_in[3];
  const float* bk = (const float*)d_in[4];
  const float* Wv = (const float*)d_in[5];
  const float* bv = (const float*)d_in[6];
  const float* Wo = (const float*)d_in[7];
  const float* bo = (const float*)d_in[8];
  float* out = (float*)d_out;

  const size_t per = (size_t)M * D;
  short* WqT = (short*)d_ws;
  short* WkT = WqT + 256 * 256;
  short* WvT = WkT + 256 * 256;
  short* WoT = WvT + 256 * 256;
  short* Qbf = WoT + 256 * 256;
  short* Kbf = Qbf + per;
  short* Vt  = Kbf + per;          // [bh][d][s]
  short* Abf = Vt + per;

  prep_w_kernel<<<64, 256, 0, stream>>>(Wq, Wk, Wv, Wo, WqT, WkT, WvT, WoT);
  gemm_qkv_kernel<<<dim3(256, 3), 256, 0, stream>>>(x, WqT, WkT, WvT, bq, bk, bv,
                                                    Qbf, Kbf, Vt);
  attn_kernel13<<<512, 256, 0, stream>>>(Qbf, Kbf, Vt, Abf);
  gemm_out_kernel<<<256, 256, 0, stream>>>(Abf, WoT, bo, out);
}

// Round 16
// 83.561 us; speedup vs baseline: 2.9401x; 1.0551x over previous
//
#include <hip/hip_runtime.h>
#include <hip/hip_bf16.h>

namespace {

constexpr int B_ = 8, S = 2048, D = 256, H = 4, HD = 64;
constexpr int M = B_ * S;  // 16384

typedef __attribute__((ext_vector_type(8))) short bf16x8;
typedef __attribute__((ext_vector_type(4))) short bf16x4;
typedef __attribute__((ext_vector_type(4))) float f32x4;
typedef __attribute__((ext_vector_type(16))) float f32x16;
typedef __attribute__((ext_vector_type(4))) unsigned uint4v;

__device__ inline short f2bf(float x) {
  __hip_bfloat16 h = __float2bfloat16(x);
  short s;
  __builtin_memcpy(&s, &h, 2);
  return s;
}

__device__ inline f32x4 mfma16(bf16x8 a, bf16x8 b, f32x4 c) {
  return __builtin_amdgcn_mfma_f32_16x16x32_bf16(a, b, c, 0, 0, 0);
}
__device__ inline f32x16 mfma32(bf16x8 a, bf16x8 b, f32x16 c) {
  return __builtin_amdgcn_mfma_f32_32x32x16_bf16(a, b, c, 0, 0, 0);
}

// raw 2^x
__device__ inline float exp2a(float x) {
  float r;
  asm("v_exp_f32 %0, %1" : "=v"(r) : "v"(x));
  return r;
}

// HW packed f32x2 -> bf16x2 (RNE)
__device__ inline unsigned cvtpk(float lo, float hi) {
  unsigned r;
  asm("v_cvt_pk_bf16_f32 %0, %1, %2" : "=v"(r) : "v"(lo), "v"(hi));
  return r;
}

__device__ inline bf16x4 pk4(float a, float b, float c, float d) {
  unsigned lo = cvtpk(a, b), hi = cvtpk(c, d);
  uint2 u{lo, hi};
  bf16x4 r;
  __builtin_memcpy(&r, &u, 8);
  return r;
}

// load 8 fp32, convert to bf16x8
__device__ inline bf16x8 ld_cvt8(const float* p) {
  float4 a = *(const float4*)p;
  float4 b = *(const float4*)(p + 4);
  uint4v u = {cvtpk(a.x, a.y), cvtpk(a.z, a.w), cvtpk(b.x, b.y), cvtpk(b.z, b.w)};
  bf16x8 r;
  __builtin_memcpy(&r, &u, 16);
  return r;
}

// ---------------------------------------------------------------------------
// Prep: 64 blocks transpose W{q,k,v,o} fp32[k][n] -> bf16 Wt[n][k].
// ---------------------------------------------------------------------------
__global__ __launch_bounds__(256) void prep_w_kernel(
    const float* __restrict__ Wq, const float* __restrict__ Wk,
    const float* __restrict__ Wv, const float* __restrict__ Wo,
    short* __restrict__ WqT, short* __restrict__ WkT,
    short* __restrict__ WvT, short* __restrict__ WoT) {
  const int blk = blockIdx.x, t = threadIdx.x;
  const int wq = blk >> 4, n0 = (blk & 15) * 16;
  const float* W = wq == 0 ? Wq : wq == 1 ? Wk : wq == 2 ? Wv : Wo;
  short* Wt = wq == 0 ? WqT : wq == 1 ? WkT : wq == 2 ? WvT : WoT;
#pragma unroll
  for (int j4 = 0; j4 < 4; ++j4) {
    float4 v = *(const float4*)(W + (size_t)t * 256 + n0 + j4 * 4);
    Wt[(n0 + j4 * 4 + 0) * 256 + t] = f2bf(v.x);
    Wt[(n0 + j4 * 4 + 1) * 256 + t] = f2bf(v.y);
    Wt[(n0 + j4 * 4 + 2) * 256 + t] = f2bf(v.z);
    Wt[(n0 + j4 * 4 + 3) * 256 + t] = f2bf(v.w);
  }
}

// ---------------------------------------------------------------------------
// QKV GEMM: x staged fp32 -> cvt_pk -> LDS. Q scale folds 1/8*log2e;
// V written [bh][d][s] via operand swap.
// ---------------------------------------------------------------------------
__global__ __launch_bounds__(256) void gemm_qkv_kernel(
    const float* __restrict__ x,
    const short* __restrict__ WqT, const short* __restrict__ WkT,
    const short* __restrict__ WvT,
    const float* __restrict__ bq, const float* __restrict__ bk,
    const float* __restrict__ bv,
    short* __restrict__ Qo, short* __restrict__ Ko, short* __restrict__ Vt) {
  const int bx = blockIdx.x;
  const int which = blockIdx.y;
  const short* Wt = which == 0 ? WqT : which == 1 ? WkT : WvT;
  const float* bias = which == 0 ? bq : which == 1 ? bk : bv;

  __shared__ short Xs[2][64 * 32];
  __shared__ short Ws[2][256 * 32];

  const int tid = threadIdx.x;
  const int wid = tid >> 6, lane = tid & 63;
  const int l15 = lane & 15, l4 = lane >> 4;
  const int nt0 = wid * 4;

  const float* xsrc = x + ((size_t)(bx * 64 + (tid >> 2))) * 256 + (tid & 3) * 8;
  const short* wsrc = Wt + ((size_t)(tid >> 2)) * 256 + (tid & 3) * 8;
  short* xdst0 = &Xs[0][tid * 8];
  short* xdst1 = &Xs[1][tid * 8];
  short* wdst0 = &Ws[0][tid * 8];
  short* wdst1 = &Ws[1][tid * 8];

  bf16x8 xr, wr[4];
  xr = ld_cvt8(xsrc);
#pragma unroll
  for (int p = 0; p < 4; ++p) wr[p] = *(const bf16x8*)(wsrc + (size_t)p * 64 * 256);
  *(bf16x8*)xdst0 = xr;
#pragma unroll
  for (int p = 0; p < 4; ++p) *(bf16x8*)(wdst0 + p * 2048) = wr[p];
  __syncthreads();

  f32x4 acc[4][4];
#pragma unroll
  for (int i = 0; i < 4; ++i)
#pragma unroll
    for (int mh = 0; mh < 4; ++mh) acc[i][mh] = f32x4{0.f, 0.f, 0.f, 0.f};

  for (int ks = 0; ks < 8; ++ks) {
    const int cur = ks & 1;
    if (ks < 7) {
      xr = ld_cvt8(xsrc + (ks + 1) * 32);
#pragma unroll
      for (int p = 0; p < 4; ++p)
        wr[p] = *(const bf16x8*)(wsrc + (size_t)p * 64 * 256 + (ks + 1) * 32);
    }
    bf16x8 wf[4], xf[4];
#pragma unroll
    for (int i = 0; i < 4; ++i)
      wf[i] = *(const bf16x8*)&Ws[cur][((nt0 + i) * 16 + l15) * 32 + l4 * 8];
#pragma unroll
    for (int mh = 0; mh < 4; ++mh)
      xf[mh] = *(const bf16x8*)&Xs[cur][(mh * 16 + l15) * 32 + l4 * 8];
    if (which == 2) {
#pragma unroll
      for (int i = 0; i < 4; ++i)
#pragma unroll
        for (int mh = 0; mh < 4; ++mh)
          acc[i][mh] = mfma16(xf[mh], wf[i], acc[i][mh]);  // D[m][n]
    } else {
#pragma unroll
      for (int i = 0; i < 4; ++i)
#pragma unroll
        for (int mh = 0; mh < 4; ++mh)
          acc[i][mh] = mfma16(wf[i], xf[mh], acc[i][mh]);  // D[n][m]
    }
    if (ks < 7) {
      short* xd = (cur ? xdst0 : xdst1);
      short* wd = (cur ? wdst0 : wdst1);
      *(bf16x8*)xd = xr;
#pragma unroll
      for (int p = 0; p < 4; ++p) *(bf16x8*)(wd + p * 2048) = wr[p];
    }
    __syncthreads();
  }

  if (which == 2) {
    const int m0 = bx * 64 + l4 * 4;
#pragma unroll
    for (int i = 0; i < 4; ++i) {
      const int n = (nt0 + i) * 16 + l15;
      const float bi = bias[n];
      const int h = n >> 6, d = n & 63;
#pragma unroll
      for (int mh = 0; mh < 4; ++mh) {
        const int m = m0 + mh * 16;
        const int bb = m >> 11, s0 = m & 2047;
        bf16x4 r = pk4(acc[i][mh][0] + bi, acc[i][mh][1] + bi,
                       acc[i][mh][2] + bi, acc[i][mh][3] + bi);
        *(bf16x4*)(Vt + (((size_t)bb * H + h) * HD + d) * S + s0) = r;
      }
    }
  } else {
    const float scale = which == 0 ? 0.18033688011112042f : 1.0f;  // 1/8*log2e
    short* outp = which == 0 ? Qo : Ko;
#pragma unroll
    for (int i = 0; i < 4; ++i) {
      const int n0 = (nt0 + i) * 16 + l4 * 4;
      float4 bi = *(const float4*)(bias + n0);
      const int h = n0 >> 6, d0 = n0 & 63;
#pragma unroll
      for (int mh = 0; mh < 4; ++mh) {
        const int m = bx * 64 + mh * 16 + l15;
        const int bb = m >> 11, s = m & 2047;
        bf16x4 r = pk4((acc[i][mh][0] + bi.x) * scale, (acc[i][mh][1] + bi.y) * scale,
                       (acc[i][mh][2] + bi.z) * scale, (acc[i][mh][3] + bi.w) * scale);
        *(bf16x4*)(outp + (((size_t)bb * H + h) * S + s) * HD + d0) = r;
      }
    }
  }
}

// ---------------------------------------------------------------------------
// Out projection GEMM (bf16 A in, fp32 out)
// ---------------------------------------------------------------------------
__global__ __launch_bounds__(256) void gemm_out_kernel(
    const short* __restrict__ Abf, const short* __restrict__ WoT,
    const float* __restrict__ bo, float* __restrict__ out) {
  const int bx = blockIdx.x;
  __shared__ short Xs[2][64 * 32];
  __shared__ short Ws[2][256 * 32];

  const int tid = threadIdx.x;
  const int wid = tid >> 6, lane = tid & 63;
  const int l15 = lane & 15, l4 = lane >> 4;
  const int nt0 = wid * 4;

  const short* xsrc = Abf + ((size_t)(bx * 64 + (tid >> 2))) * 256 + (tid & 3) * 8;
  const short* wsrc = WoT + ((size_t)(tid >> 2)) * 256 + (tid & 3) * 8;
  short* xdst0 = &Xs[0][tid * 8];
  short* xdst1 = &Xs[1][tid * 8];
  short* wdst0 = &Ws[0][tid * 8];
  short* wdst1 = &Ws[1][tid * 8];

  bf16x8 xr, wr[4];
  xr = *(const bf16x8*)xsrc;
#pragma unroll
  for (int p = 0; p < 4; ++p) wr[p] = *(const bf16x8*)(wsrc + (size_t)p * 64 * 256);
  *(bf16x8*)xdst0 = xr;
#pragma unroll
  for (int p = 0; p < 4; ++p) *(bf16x8*)(wdst0 + p * 2048) = wr[p];
  __syncthreads();

  f32x4 acc[4][4];
#pragma unroll
  for (int i = 0; i < 4; ++i)
#pragma unroll
    for (int mh = 0; mh < 4; ++mh) acc[i][mh] = f32x4{0.f, 0.f, 0.f, 0.f};

  for (int ks = 0; ks < 8; ++ks) {
    const int cur = ks & 1;
    if (ks < 7) {
      xr = *(const bf16x8*)(xsrc + (ks + 1) * 32);
#pragma unroll
      for (int p = 0; p < 4; ++p)
        wr[p] = *(const bf16x8*)(wsrc + (size_t)p * 64 * 256 + (ks + 1) * 32);
    }
    bf16x8 wf[4], xf[4];
#pragma unroll
    for (int i = 0; i < 4; ++i)
      wf[i] = *(const bf16x8*)&Ws[cur][((nt0 + i) * 16 + l15) * 32 + l4 * 8];
#pragma unroll
    for (int mh = 0; mh < 4; ++mh)
      xf[mh] = *(const bf16x8*)&Xs[cur][(mh * 16 + l15) * 32 + l4 * 8];
#pragma unroll
    for (int i = 0; i < 4; ++i)
#pragma unroll
      for (int mh = 0; mh < 4; ++mh)
        acc[i][mh] = mfma16(wf[i], xf[mh], acc[i][mh]);
    if (ks < 7) {
      short* xd = (cur ? xdst0 : xdst1);
      short* wd = (cur ? wdst0 : wdst1);
      *(bf16x8*)xd = xr;
#pragma unroll
      for (int p = 0; p < 4; ++p) *(bf16x8*)(wd + p * 2048) = wr[p];
    }
    __syncthreads();
  }

#pragma unroll
  for (int i = 0; i < 4; ++i) {
    const int n0 = (nt0 + i) * 16 + l4 * 4;
    float4 bi = *(const float4*)(bo + n0);
#pragma unroll
    for (int mh = 0; mh < 4; ++mh) {
      const int m = bx * 64 + mh * 16 + l15;
      float4 r;
      r.x = acc[i][mh][0] + bi.x;
      r.y = acc[i][mh][1] + bi.y;
      r.z = acc[i][mh][2] + bi.z;
      r.w = acc[i][mh][3] + bi.w;
      *(float4*)(out + (size_t)m * 256 + n0) = r;
    }
  }
}

// ---------------------------------------------------------------------------
// Flash attention v14: EXP-DEFERRED pipeline. Iteration t runs QK(t) (MFMA,
// -> sc_new) CONCURRENTLY with exp/pack(sc(t-1)) (VALU) -- register-
// independent, so the scheduler co-issues on separate pipes -- then
// PV(t-1) with the fresh pB. sc ping-pongs via 2x unroll (no runtime
// indexing). V triple-buffered, K double-buffered, 1 barrier/tile (R15).
// O/l accumulate identical terms; epilogue handles exp+PV of tile NT-1.
// ---------------------------------------------------------------------------
__global__ __launch_bounds__(256) void attn_kernel14(
    const short* __restrict__ Q, const short* __restrict__ K,
    const short* __restrict__ VT, short* __restrict__ Abf) {
  const int lin = blockIdx.x;   // 512
  const int bh = lin & 31;      // same-bh blocks land on same XCD
  const int qt = lin >> 5;      // 0..15
  const int tid = threadIdx.x, wid = tid >> 6, lane = tid & 63;
  const int q31 = lane & 31, h = lane >> 5;
  constexpr int NT = S / 64;  // 32

  __shared__ short Ks[2][64 * 128];  // [kv][d], swizzled, pitch 128
  __shared__ short Vs[3][64 * 128];  // [d][kv], swizzled, pitch 128

  const short* Kg = K + (size_t)bh * S * HD;
  const short* Vg = VT + (size_t)bh * HD * S;
  const int qrow = qt * 128 + wid * 32;

  const short* Qg = Q + ((size_t)bh * S + qrow + q31) * HD + h * 8;
  bf16x8 qf[4];
#pragma unroll
  for (int ds = 0; ds < 4; ++ds) qf[ds] = *(const bf16x8*)(Qg + ds * 16);

  bf16x8 ones;
#pragma unroll
  for (int i = 0; i < 8; ++i) ones[i] = (short)0x3F80;

  const int srow = tid >> 2;
  const int scol = (tid & 3) * 16;
  const int swz = (srow & 15) * 8;
  const int c0 = scol ^ swz;
  const int c1 = (scol + 8) ^ swz;

  const int fs = (lane & 15) * 8;
  int kcol[4];
#pragma unroll
  for (int ds = 0; ds < 4; ++ds) kcol[ds] = (ds * 16 + h * 8) ^ fs;

  // ---- prologue: stage K(0) -> Ks[0]; issue loads K(1), V(0); barrier ----
  bf16x8 kr0, kr1, vr0, vr1;
  kr0 = *(const bf16x8*)(Kg + (size_t)srow * HD + scol);
  kr1 = *(const bf16x8*)(Kg + (size_t)srow * HD + scol + 8);
  *(bf16x8*)&Ks[0][srow * 128 + c0] = kr0;
  *(bf16x8*)&Ks[0][srow * 128 + c1] = kr1;
  {
    const short* Kn = Kg + (size_t)64 * HD;
    kr0 = *(const bf16x8*)(Kn + (size_t)srow * HD + scol);
    kr1 = *(const bf16x8*)(Kn + (size_t)srow * HD + scol + 8);
    vr0 = *(const bf16x8*)(Vg + (size_t)srow * S + scol);
    vr1 = *(const bf16x8*)(Vg + (size_t)srow * S + scol + 8);
  }
  __syncthreads();

  f32x16 o0, o1, lsum, scA0, scA1, scB0, scB1;
#pragma unroll
  for (int i = 0; i < 16; ++i) { o0[i] = 0.f; o1[i] = 0.f; lsum[i] = 0.f; }
  bf16x8 pB[4];

#define EXPPACK(S0, S1)                                               \
  {                                                                   \
    _Pragma("unroll") for (int win = 0; win < 2; ++win) {             \
      const f32x16& sc = win ? (S1) : (S0);                           \
      float p[16];                                                    \
      _Pragma("unroll") for (int r = 0; r < 16; ++r)                  \
          p[r] = exp2a(sc[r]);                                        \
      unsigned w[8];                                                  \
      _Pragma("unroll") for (int i = 0; i < 8; ++i)                   \
          w[i] = cvtpk(p[2 * i], p[2 * i + 1]);                       \
      unsigned x0 = w[0], y0 = w[2], x1 = w[1], y1 = w[3];            \
      unsigned x2 = w[4], y2 = w[6], x3 = w[5], y3 = w[7];            \
      asm("v_permlane32_swap_b32 %0, %1" : "+v"(x0), "+v"(y0));       \
      asm("v_permlane32_swap_b32 %0, %1" : "+v"(x1), "+v"(y1));       \
      asm("v_permlane32_swap_b32 %0, %1" : "+v"(x2), "+v"(y2));       \
      asm("v_permlane32_swap_b32 %0, %1" : "+v"(x3), "+v"(y3));       \
      uint4v u0 = {x0, x1, y0, y1};                                   \
      uint4v u1 = {x2, x3, y2, y3};                                   \
      __builtin_memcpy(&pB[win * 2 + 0], &u0, 16);                    \
      __builtin_memcpy(&pB[win * 2 + 1], &u1, 16);                    \
    }                                                                 \
  }

  // ---- peeled iteration 0: QK(0)->scA (NO exp yet); write K(1),V(0);
  //      single barrier ----
  {
#pragma unroll
    for (int i = 0; i < 16; ++i) { scA0[i] = 0.f; scA1[i] = 0.f; }
    __builtin_amdgcn_s_setprio(1);
#pragma unroll
    for (int ds = 0; ds < 4; ++ds) {
      bf16x8 k0 = *(const bf16x8*)&Ks[0][(q31)*128 + kcol[ds]];
      bf16x8 k1 = *(const bf16x8*)&Ks[0][(32 + q31) * 128 + kcol[ds]];
      scA0 = mfma32(k0, qf[ds], scA0);
      scA1 = mfma32(k1, qf[ds], scA1);
    }
    __builtin_amdgcn_s_setprio(0);
    *(bf16x8*)&Ks[1][srow * 128 + c0] = kr0;
    *(bf16x8*)&Ks[1][srow * 128 + c1] = kr1;
    *(bf16x8*)&Vs[0][srow * 128 + c0] = vr0;
    *(bf16x8*)&Vs[0][srow * 128 + c1] = vr1;
    __syncthreads();
  }

  int vrd = 0;  // (t-1)%3 at loop top
  int vwr = 1;  // t%3

  // STEP(KT): loads; QK(KT)->SCN (MFMA) || exp/pack(SCP)->pB (VALU);
  //           PV(KT-1) from Vs[vrd]; writes; barrier.
#define STEP(KT, SCP0, SCP1, SCN0, SCN1)                                   \
  {                                                                        \
    if ((KT) + 1 < NT) {                                                   \
      const short* Kn = Kg + (size_t)((KT) + 1) * 64 * HD;                 \
      kr0 = *(const bf16x8*)(Kn + (size_t)srow * HD + scol);               \
      kr1 = *(const bf16x8*)(Kn + (size_t)srow * HD + scol + 8);           \
    }                                                                      \
    vr0 = *(const bf16x8*)(Vg + (size_t)srow * S + (KT) * 64 + scol);      \
    vr1 = *(const bf16x8*)(Vg + (size_t)srow * S + (KT) * 64 + scol + 8);  \
    _Pragma("unroll") for (int i = 0; i < 16; ++i) {                       \
      SCN0[i] = 0.f;                                                       \
      SCN1[i] = 0.f;                                                       \
    }                                                                      \
    {                                                                      \
      const short* kb = &Ks[(KT)&1][0];                                    \
      _Pragma("unroll") for (int ds = 0; ds < 4; ++ds) {                   \
        bf16x8 k0 = *(const bf16x8*)&kb[(q31)*128 + kcol[ds]];             \
        bf16x8 k1 = *(const bf16x8*)&kb[(32 + q31) * 128 + kcol[ds]];      \
        SCN0 = mfma32(k0, qf[ds], SCN0);                                   \
        SCN1 = mfma32(k1, qf[ds], SCN1);                                   \
      }                                                                    \
    }                                                                      \
    EXPPACK(SCP0, SCP1);                                                   \
    {                                                                      \
      const short* vb = &Vs[vrd][0];                                       \
      __builtin_amdgcn_s_setprio(1);                                       \
      _Pragma("unroll") for (int ds = 0; ds < 4; ++ds) {                   \
        bf16x8 v0 = *(const bf16x8*)&vb[(q31)*128 + kcol[ds]];             \
        bf16x8 v1 = *(const bf16x8*)&vb[(32 + q31) * 128 + kcol[ds]];      \
        o0 = mfma32(v0, pB[ds], o0);                                       \
        o1 = mfma32(v1, pB[ds], o1);                                       \
        lsum = mfma32(ones, pB[ds], lsum);                                 \
      }                                                                    \
      __builtin_amdgcn_s_setprio(0);                                       \
    }                                                                      \
    if ((KT) + 1 < NT) {                                                   \
      short* kw = &Ks[((KT) + 1) & 1][0];                                  \
      *(bf16x8*)&kw[srow * 128 + c0] = kr0;                                \
      *(bf16x8*)&kw[srow * 128 + c1] = kr1;                                \
    }                                                                      \
    {                                                                      \
      short* vw = &Vs[vwr][0];                                             \
      *(bf16x8*)&vw[srow * 128 + c0] = vr0;                                \
      *(bf16x8*)&vw[srow * 128 + c1] = vr1;                                \
    }                                                                      \
    __syncthreads();                                                       \
    vrd = vwr;                                                             \
    vwr = (vwr == 2) ? 0 : vwr + 1;                                        \
  }

  // ---- main loop: t = 1..30 in ping-pong pairs, then t = 31 ----
  for (int kt = 1; kt < NT - 1; kt += 2) {
    STEP(kt, scA0, scA1, scB0, scB1);
    STEP(kt + 1, scB0, scB1, scA0, scA1);
  }
  STEP(NT - 1, scA0, scA1, scB0, scB1);

  // ---- epilogue: exp(sc(NT-1)) -> pB; PV(NT-1) from Vs[vrd] ----
  {
    EXPPACK(scB0, scB1);
    const short* vb = &Vs[vrd][0];
    __builtin_amdgcn_s_setprio(1);
#pragma unroll
    for (int ds = 0; ds < 4; ++ds) {
      bf16x8 v0 = *(const bf16x8*)&vb[(q31)*128 + kcol[ds]];
      bf16x8 v1 = *(const bf16x8*)&vb[(32 + q31) * 128 + kcol[ds]];
      o0 = mfma32(v0, pB[ds], o0);
      o1 = mfma32(v1, pB[ds], o1);
      lsum = mfma32(ones, pB[ds], lsum);
    }
    __builtin_amdgcn_s_setprio(0);
  }
#undef STEP
#undef EXPPACK

  // lsum[0] = full column sum for this lane's q
  const float inv = 1.0f / lsum[0];
  const int b = bh >> 2, hh = bh & 3;
  short* ap = Abf + ((size_t)b * S + qrow + q31) * 256 + hh * 64;
#pragma unroll
  for (int dt = 0; dt < 2; ++dt) {
    const f32x16& o = dt ? o1 : o0;
#pragma unroll
    for (int g = 0; g < 4; ++g) {
      const int d0 = dt * 32 + 8 * g + 4 * h;
      bf16x4 r = pk4(o[4 * g + 0] * inv, o[4 * g + 1] * inv,
                     o[4 * g + 2] * inv, o[4 * g + 3] * inv);
      *(bf16x4*)(ap + d0) = r;
    }
  }
}

}  // namespace

extern "C" void kernel_launch(void* const* d_in, const int* in_sizes, int n_in,
                              void* d_out, int out_size, void* d_ws, size_t ws_size,
                              hipStream_t stream) {
  const float* x  = (const float*)d_in[0];
  const float* Wq = (const float*)d_in[1];
  const float* bq = (const float*)d_in[2];
  const float* Wk = (const float*)d_in[3];
  const float* bk = (const float*)d_in[4];
  const float* Wv = (const float*)d_in[5];
  const float* bv = (const float*)d_in[6];
  const float* Wo = (const float*)d_in[7];
  const float* bo = (const float*)d_in[8];
  float* out = (float*)d_out;

  const size_t per = (size_t)M * D;
  short* WqT = (short*)d_ws;
  short* WkT = WqT + 256 * 256;
  short* WvT = WkT + 256 * 256;
  short* WoT = WvT + 256 * 256;
  short* Qbf = WoT + 256 * 256;
  short* Kbf = Qbf + per;
  short* Vt  = Kbf + per;          // [bh][d][s]
  short* Abf = Vt + per;

  prep_w_kernel<<<64, 256, 0, stream>>>(Wq, Wk, Wv, Wo, WqT, WkT, WvT, WoT);
  gemm_qkv_kernel<<<dim3(256, 3), 256, 0, stream>>>(x, WqT, WkT, WvT, bq, bk, bv,
                                                    Qbf, Kbf, Vt);
  attn_kernel14<<<512, 256, 0, stream>>>(Qbf, Kbf, Vt, Abf);
  gemm_out_kernel<<<256, 256, 0, stream>>>(Abf, WoT, bo, out);
}

// Round 17
// 83.183 us; speedup vs baseline: 2.9535x; 1.0045x over previous
//
#include <hip/hip_runtime.h>
#include <hip/hip_bf16.h>

namespace {

constexpr int B_ = 8, S = 2048, D = 256, H = 4, HD = 64;
constexpr int M = B_ * S;  // 16384

typedef __attribute__((ext_vector_type(8))) short bf16x8;
typedef __attribute__((ext_vector_type(4))) short bf16x4;
typedef __attribute__((ext_vector_type(4))) float f32x4;
typedef __attribute__((ext_vector_type(16))) float f32x16;
typedef __attribute__((ext_vector_type(4))) unsigned uint4v;

__device__ inline short f2bf(float x) {
  __hip_bfloat16 h = __float2bfloat16(x);
  short s;
  __builtin_memcpy(&s, &h, 2);
  return s;
}

__device__ inline f32x4 mfma16(bf16x8 a, bf16x8 b, f32x4 c) {
  return __builtin_amdgcn_mfma_f32_16x16x32_bf16(a, b, c, 0, 0, 0);
}
__device__ inline f32x16 mfma32(bf16x8 a, bf16x8 b, f32x16 c) {
  return __builtin_amdgcn_mfma_f32_32x32x16_bf16(a, b, c, 0, 0, 0);
}

// raw 2^x
__device__ inline float exp2a(float x) {
  float r;
  asm("v_exp_f32 %0, %1" : "=v"(r) : "v"(x));
  return r;
}

// HW packed f32x2 -> bf16x2 (RNE)
__device__ inline unsigned cvtpk(float lo, float hi) {
  unsigned r;
  asm("v_cvt_pk_bf16_f32 %0, %1, %2" : "=v"(r) : "v"(lo), "v"(hi));
  return r;
}

__device__ inline bf16x4 pk4(float a, float b, float c, float d) {
  unsigned lo = cvtpk(a, b), hi = cvtpk(c, d);
  uint2 u{lo, hi};
  bf16x4 r;
  __builtin_memcpy(&r, &u, 8);
  return r;
}

// load 8 fp32, convert to bf16x8
__device__ inline bf16x8 ld_cvt8(const float* p) {
  float4 a = *(const float4*)p;
  float4 b = *(const float4*)(p + 4);
  uint4v u = {cvtpk(a.x, a.y), cvtpk(a.z, a.w), cvtpk(b.x, b.y), cvtpk(b.z, b.w)};
  bf16x8 r;
  __builtin_memcpy(&r, &u, 16);
  return r;
}

// ---------------------------------------------------------------------------
// Prep: 64 blocks transpose W{q,k,v,o} fp32[k][n] -> bf16 Wt[n][k].
// ---------------------------------------------------------------------------
__global__ __launch_bounds__(256) void prep_w_kernel(
    const float* __restrict__ Wq, const float* __restrict__ Wk,
    const float* __restrict__ Wv, const float* __restrict__ Wo,
    short* __restrict__ WqT, short* __restrict__ WkT,
    short* __restrict__ WvT, short* __restrict__ WoT) {
  const int blk = blockIdx.x, t = threadIdx.x;
  const int wq = blk >> 4, n0 = (blk & 15) * 16;
  const float* W = wq == 0 ? Wq : wq == 1 ? Wk : wq == 2 ? Wv : Wo;
  short* Wt = wq == 0 ? WqT : wq == 1 ? WkT : wq == 2 ? WvT : WoT;
#pragma unroll
  for (int j4 = 0; j4 < 4; ++j4) {
    float4 v = *(const float4*)(W + (size_t)t * 256 + n0 + j4 * 4);
    Wt[(n0 + j4 * 4 + 0) * 256 + t] = f2bf(v.x);
    Wt[(n0 + j4 * 4 + 1) * 256 + t] = f2bf(v.y);
    Wt[(n0 + j4 * 4 + 2) * 256 + t] = f2bf(v.z);
    Wt[(n0 + j4 * 4 + 3) * 256 + t] = f2bf(v.w);
  }
}

// ---------------------------------------------------------------------------
// QKV GEMM: x staged fp32 -> cvt_pk -> LDS. Q scale folds 1/8*log2e;
// V written [bh][d][s] via operand swap.
// ---------------------------------------------------------------------------
__global__ __launch_bounds__(256) void gemm_qkv_kernel(
    const float* __restrict__ x,
    const short* __restrict__ WqT, const short* __restrict__ WkT,
    const short* __restrict__ WvT,
    const float* __restrict__ bq, const float* __restrict__ bk,
    const float* __restrict__ bv,
    short* __restrict__ Qo, short* __restrict__ Ko, short* __restrict__ Vt) {
  const int bx = blockIdx.x;
  const int which = blockIdx.y;
  const short* Wt = which == 0 ? WqT : which == 1 ? WkT : WvT;
  const float* bias = which == 0 ? bq : which == 1 ? bk : bv;

  __shared__ short Xs[2][64 * 32];
  __shared__ short Ws[2][256 * 32];

  const int tid = threadIdx.x;
  const int wid = tid >> 6, lane = tid & 63;
  const int l15 = lane & 15, l4 = lane >> 4;
  const int nt0 = wid * 4;

  const float* xsrc = x + ((size_t)(bx * 64 + (tid >> 2))) * 256 + (tid & 3) * 8;
  const short* wsrc = Wt + ((size_t)(tid >> 2)) * 256 + (tid & 3) * 8;
  short* xdst0 = &Xs[0][tid * 8];
  short* xdst1 = &Xs[1][tid * 8];
  short* wdst0 = &Ws[0][tid * 8];
  short* wdst1 = &Ws[1][tid * 8];

  bf16x8 xr, wr[4];
  xr = ld_cvt8(xsrc);
#pragma unroll
  for (int p = 0; p < 4; ++p) wr[p] = *(const bf16x8*)(wsrc + (size_t)p * 64 * 256);
  *(bf16x8*)xdst0 = xr;
#pragma unroll
  for (int p = 0; p < 4; ++p) *(bf16x8*)(wdst0 + p * 2048) = wr[p];
  __syncthreads();

  f32x4 acc[4][4];
#pragma unroll
  for (int i = 0; i < 4; ++i)
#pragma unroll
    for (int mh = 0; mh < 4; ++mh) acc[i][mh] = f32x4{0.f, 0.f, 0.f, 0.f};

  for (int ks = 0; ks < 8; ++ks) {
    const int cur = ks & 1;
    if (ks < 7) {
      xr = ld_cvt8(xsrc + (ks + 1) * 32);
#pragma unroll
      for (int p = 0; p < 4; ++p)
        wr[p] = *(const bf16x8*)(wsrc + (size_t)p * 64 * 256 + (ks + 1) * 32);
    }
    bf16x8 wf[4], xf[4];
#pragma unroll
    for (int i = 0; i < 4; ++i)
      wf[i] = *(const bf16x8*)&Ws[cur][((nt0 + i) * 16 + l15) * 32 + l4 * 8];
#pragma unroll
    for (int mh = 0; mh < 4; ++mh)
      xf[mh] = *(const bf16x8*)&Xs[cur][(mh * 16 + l15) * 32 + l4 * 8];
    if (which == 2) {
#pragma unroll
      for (int i = 0; i < 4; ++i)
#pragma unroll
        for (int mh = 0; mh < 4; ++mh)
          acc[i][mh] = mfma16(xf[mh], wf[i], acc[i][mh]);  // D[m][n]
    } else {
#pragma unroll
      for (int i = 0; i < 4; ++i)
#pragma unroll
        for (int mh = 0; mh < 4; ++mh)
          acc[i][mh] = mfma16(wf[i], xf[mh], acc[i][mh]);  // D[n][m]
    }
    if (ks < 7) {
      short* xd = (cur ? xdst0 : xdst1);
      short* wd = (cur ? wdst0 : wdst1);
      *(bf16x8*)xd = xr;
#pragma unroll
      for (int p = 0; p < 4; ++p) *(bf16x8*)(wd + p * 2048) = wr[p];
    }
    __syncthreads();
  }

  if (which == 2) {
    const int m0 = bx * 64 + l4 * 4;
#pragma unroll
    for (int i = 0; i < 4; ++i) {
      const int n = (nt0 + i) * 16 + l15;
      const float bi = bias[n];
      const int h = n >> 6, d = n & 63;
#pragma unroll
      for (int mh = 0; mh < 4; ++mh) {
        const int m = m0 + mh * 16;
        const int bb = m >> 11, s0 = m & 2047;
        bf16x4 r = pk4(acc[i][mh][0] + bi, acc[i][mh][1] + bi,
                       acc[i][mh][2] + bi, acc[i][mh][3] + bi);
        *(bf16x4*)(Vt + (((size_t)bb * H + h) * HD + d) * S + s0) = r;
      }
    }
  } else {
    const float scale = which == 0 ? 0.18033688011112042f : 1.0f;  // 1/8*log2e
    short* outp = which == 0 ? Qo : Ko;
#pragma unroll
    for (int i = 0; i < 4; ++i) {
      const int n0 = (nt0 + i) * 16 + l4 * 4;
      float4 bi = *(const float4*)(bias + n0);
      const int h = n0 >> 6, d0 = n0 & 63;
#pragma unroll
      for (int mh = 0; mh < 4; ++mh) {
        const int m = bx * 64 + mh * 16 + l15;
        const int bb = m >> 11, s = m & 2047;
        bf16x4 r = pk4((acc[i][mh][0] + bi.x) * scale, (acc[i][mh][1] + bi.y) * scale,
                       (acc[i][mh][2] + bi.z) * scale, (acc[i][mh][3] + bi.w) * scale);
        *(bf16x4*)(outp + (((size_t)bb * H + h) * S + s) * HD + d0) = r;
      }
    }
  }
}

// ---------------------------------------------------------------------------
// Out projection GEMM (bf16 A in, fp32 out)
// ---------------------------------------------------------------------------
__global__ __launch_bounds__(256) void gemm_out_kernel(
    const short* __restrict__ Abf, const short* __restrict__ WoT,
    const float* __restrict__ bo, float* __restrict__ out) {
  const int bx = blockIdx.x;
  __shared__ short Xs[2][64 * 32];
  __shared__ short Ws[2][256 * 32];

  const int tid = threadIdx.x;
  const int wid = tid >> 6, lane = tid & 63;
  const int l15 = lane & 15, l4 = lane >> 4;
  const int nt0 = wid * 4;

  const short* xsrc = Abf + ((size_t)(bx * 64 + (tid >> 2))) * 256 + (tid & 3) * 8;
  const short* wsrc = WoT + ((size_t)(tid >> 2)) * 256 + (tid & 3) * 8;
  short* xdst0 = &Xs[0][tid * 8];
  short* xdst1 = &Xs[1][tid * 8];
  short* wdst0 = &Ws[0][tid * 8];
  short* wdst1 = &Ws[1][tid * 8];

  bf16x8 xr, wr[4];
  xr = *(const bf16x8*)xsrc;
#pragma unroll
  for (int p = 0; p < 4; ++p) wr[p] = *(const bf16x8*)(wsrc + (size_t)p * 64 * 256);
  *(bf16x8*)xdst0 = xr;
#pragma unroll
  for (int p = 0; p < 4; ++p) *(bf16x8*)(wdst0 + p * 2048) = wr[p];
  __syncthreads();

  f32x4 acc[4][4];
#pragma unroll
  for (int i = 0; i < 4; ++i)
#pragma unroll
    for (int mh = 0; mh < 4; ++mh) acc[i][mh] = f32x4{0.f, 0.f, 0.f, 0.f};

  for (int ks = 0; ks < 8; ++ks) {
    const int cur = ks & 1;
    if (ks < 7) {
      xr = *(const bf16x8*)(xsrc + (ks + 1) * 32);
#pragma unroll
      for (int p = 0; p < 4; ++p)
        wr[p] = *(const bf16x8*)(wsrc + (size_t)p * 64 * 256 + (ks + 1) * 32);
    }
    bf16x8 wf[4], xf[4];
#pragma unroll
    for (int i = 0; i < 4; ++i)
      wf[i] = *(const bf16x8*)&Ws[cur][((nt0 + i) * 16 + l15) * 32 + l4 * 8];
#pragma unroll
    for (int mh = 0; mh < 4; ++mh)
      xf[mh] = *(const bf16x8*)&Xs[cur][(mh * 16 + l15) * 32 + l4 * 8];
#pragma unroll
    for (int i = 0; i < 4; ++i)
#pragma unroll
      for (int mh = 0; mh < 4; ++mh)
        acc[i][mh] = mfma16(wf[i], xf[mh], acc[i][mh]);
    if (ks < 7) {
      short* xd = (cur ? xdst0 : xdst1);
      short* wd = (cur ? wdst0 : wdst1);
      *(bf16x8*)xd = xr;
#pragma unroll
      for (int p = 0; p < 4; ++p) *(bf16x8*)(wd + p * 2048) = wr[p];
    }
    __syncthreads();
  }

#pragma unroll
  for (int i = 0; i < 4; ++i) {
    const int n0 = (nt0 + i) * 16 + l4 * 4;
    float4 bi = *(const float4*)(bo + n0);
#pragma unroll
    for (int mh = 0; mh < 4; ++mh) {
      const int m = bx * 64 + mh * 16 + l15;
      float4 r;
      r.x = acc[i][mh][0] + bi.x;
      r.y = acc[i][mh][1] + bi.y;
      r.z = acc[i][mh][2] + bi.z;
      r.w = acc[i][mh][3] + bi.w;
      *(float4*)(out + (size_t)m * 256 + n0) = r;
    }
  }
}

// ---------------------------------------------------------------------------
// Flash attention v15: PV DEFERRED BY 2. Iteration t issues one 28-MFMA
// burst {QK(t)->sc_new, PV(t-2) with pB_old, lsum} fully independent of the
// VALU segment {EXPPACK(sc(t-1))->pB_new}. Double ping-pong: sc x2, pB x2.
// PACKED 8KB tiles (R11/R13-verified [32][128] fold, 0 conflicts):
// K double-buffered, V triple-buffered (read lag 2: slots t-2,t-1,t distinct
// mod 3). Single barrier/tile (R15 argument). LDS 40KB/block, 2 blocks/CU.
// ---------------------------------------------------------------------------
__global__ __launch_bounds__(256) void attn_kernel15(
    const short* __restrict__ Q, const short* __restrict__ K,
    const short* __restrict__ VT, short* __restrict__ Abf) {
  const int lin = blockIdx.x;   // 512
  const int bh = lin & 31;      // same-bh blocks land on same XCD
  const int qt = lin >> 5;      // 0..15
  const int tid = threadIdx.x, wid = tid >> 6, lane = tid & 63;
  const int q31 = lane & 31, h = lane >> 5;
  constexpr int NT = S / 64;  // 32

  __shared__ short Ks[2][32 * 128];  // packed [64][64] tiles, 8KB each
  __shared__ short Vs[3][32 * 128];

  const short* Kg = K + (size_t)bh * S * HD;
  const short* Vg = VT + (size_t)bh * HD * S;
  const int qrow = qt * 128 + wid * 32;

  const short* Qg = Q + ((size_t)bh * S + qrow + q31) * HD + h * 8;
  bf16x8 qf[4];
#pragma unroll
  for (int ds = 0; ds < 4; ++ds) qf[ds] = *(const bf16x8*)(Qg + ds * 16);

  bf16x8 ones;
#pragma unroll
  for (int i = 0; i < 8; ++i) ones[i] = (short)0x3F80;

  // staging addresses (packed): logical row srow 0..63 -> phys row srow&31,
  // col bit6 = srow>>5, then ^ (pr&15)*8 swizzle
  const int srow = tid >> 2;
  const int pr = srow & 31;
  const int scol = (tid & 3) * 16;
  const int cb0 = ((srow >> 5) << 6) + scol;
  const int swz = (pr & 15) * 8;
  const int c0 = cb0 ^ swz;
  const int c1 = (cb0 + 8) ^ swz;
  const int sbase = pr * 128;

  // fragment read cols: logical rows q31 (half0) / 32+q31 (half1)
  const int fs = (q31 & 15) * 8;
  int colA[4], colB[4];
#pragma unroll
  for (int ds = 0; ds < 4; ++ds) {
    colA[ds] = (ds * 16 + h * 8) ^ fs;
    colB[ds] = (64 + ds * 16 + h * 8) ^ fs;
  }
  const int rbase = q31 * 128;

  // ---- prologue: stage K(0) -> Ks[0]; issue loads K(1), V(0); barrier ----
  bf16x8 kr0, kr1, vr0, vr1;
  kr0 = *(const bf16x8*)(Kg + (size_t)srow * HD + scol);
  kr1 = *(const bf16x8*)(Kg + (size_t)srow * HD + scol + 8);
  *(bf16x8*)&Ks[0][sbase + c0] = kr0;
  *(bf16x8*)&Ks[0][sbase + c1] = kr1;
  {
    const short* Kn = Kg + (size_t)64 * HD;
    kr0 = *(const bf16x8*)(Kn + (size_t)srow * HD + scol);
    kr1 = *(const bf16x8*)(Kn + (size_t)srow * HD + scol + 8);
    vr0 = *(const bf16x8*)(Vg + (size_t)srow * S + scol);
    vr1 = *(const bf16x8*)(Vg + (size_t)srow * S + scol + 8);
  }
  __syncthreads();

  f32x16 o0, o1, lsum, scA0, scA1, scB0, scB1;
#pragma unroll
  for (int i = 0; i < 16; ++i) { o0[i] = 0.f; o1[i] = 0.f; lsum[i] = 0.f; }
  bf16x8 pBA[4], pBB[4];

#define EXPPACK(S0, S1, PB)                                           \
  {                                                                   \
    _Pragma("unroll") for (int win = 0; win < 2; ++win) {             \
      const f32x16& sc = win ? (S1) : (S0);                           \
      float p[16];                                                    \
      _Pragma("unroll") for (int r = 0; r < 16; ++r)                  \
          p[r] = exp2a(sc[r]);                                        \
      unsigned w[8];                                                  \
      _Pragma("unroll") for (int i = 0; i < 8; ++i)                   \
          w[i] = cvtpk(p[2 * i], p[2 * i + 1]);                       \
      unsigned x0 = w[0], y0 = w[2], x1 = w[1], y1 = w[3];            \
      unsigned x2 = w[4], y2 = w[6], x3 = w[5], y3 = w[7];            \
      asm("v_permlane32_swap_b32 %0, %1" : "+v"(x0), "+v"(y0));       \
      asm("v_permlane32_swap_b32 %0, %1" : "+v"(x1), "+v"(y1));       \
      asm("v_permlane32_swap_b32 %0, %1" : "+v"(x2), "+v"(y2));       \
      asm("v_permlane32_swap_b32 %0, %1" : "+v"(x3), "+v"(y3));       \
      uint4v u0 = {x0, x1, y0, y1};                                   \
      uint4v u1 = {x2, x3, y2, y3};                                   \
      __builtin_memcpy(&PB[win * 2 + 0], &u0, 16);                    \
      __builtin_memcpy(&PB[win * 2 + 1], &u1, 16);                    \
    }                                                                 \
  }

#define QKBURST(KB, SCN0, SCN1)                                       \
  {                                                                   \
    _Pragma("unroll") for (int i = 0; i < 16; ++i) {                  \
      SCN0[i] = 0.f;                                                  \
      SCN1[i] = 0.f;                                                  \
    }                                                                 \
    const short* kb_ = (KB);                                          \
    _Pragma("unroll") for (int ds = 0; ds < 4; ++ds) {                \
      bf16x8 k0 = *(const bf16x8*)&kb_[rbase + colA[ds]];             \
      bf16x8 k1 = *(const bf16x8*)&kb_[rbase + colB[ds]];             \
      SCN0 = mfma32(k0, qf[ds], SCN0);                                \
      SCN1 = mfma32(k1, qf[ds], SCN1);                                \
    }                                                                 \
  }

#define PVBURST(VB, PB)                                               \
  {                                                                   \
    const short* vb_ = (VB);                                          \
    _Pragma("unroll") for (int ds = 0; ds < 4; ++ds) {                \
      bf16x8 v0 = *(const bf16x8*)&vb_[rbase + colA[ds]];             \
      bf16x8 v1 = *(const bf16x8*)&vb_[rbase + colB[ds]];             \
      o0 = mfma32(v0, PB[ds], o0);                                    \
      o1 = mfma32(v1, PB[ds], o1);                                    \
      lsum = mfma32(ones, PB[ds], lsum);                              \
    }                                                                 \
  }

#define STAGEWR(KT)                                                   \
  {                                                                   \
    if ((KT) + 1 < NT) {                                              \
      short* kw = &Ks[((KT) + 1) & 1][0];                             \
      *(bf16x8*)&kw[sbase + c0] = kr0;                                \
      *(bf16x8*)&kw[sbase + c1] = kr1;                                \
    }                                                                 \
    short* vw_ = &Vs[vw][0];                                          \
    *(bf16x8*)&vw_[sbase + c0] = vr0;                                 \
    *(bf16x8*)&vw_[sbase + c1] = vr1;                                 \
  }

#define LOADS(KT)                                                          \
  {                                                                        \
    if ((KT) + 1 < NT) {                                                   \
      const short* Kn = Kg + (size_t)((KT) + 1) * 64 * HD;                 \
      kr0 = *(const bf16x8*)(Kn + (size_t)srow * HD + scol);               \
      kr1 = *(const bf16x8*)(Kn + (size_t)srow * HD + scol + 8);           \
    }                                                                      \
    vr0 = *(const bf16x8*)(Vg + (size_t)srow * S + (KT) * 64 + scol);      \
    vr1 = *(const bf16x8*)(Vg + (size_t)srow * S + (KT) * 64 + scol + 8);  \
  }

  int vw = 0;  // V write slot = t % 3

  // ---- peel t=0: QK(0)->scA; write K(1),V(0); barrier ----
  {
    __builtin_amdgcn_s_setprio(1);
    QKBURST(&Ks[0][0], scA0, scA1);
    __builtin_amdgcn_s_setprio(0);
    STAGEWR(0);
    __syncthreads();
    vw = 1;
  }

  // ---- peel t=1: loads; QK(1)->scB || EXPPACK(scA)->pBA; writes; barrier ----
  {
    LOADS(1);
    __builtin_amdgcn_s_setprio(1);
    QKBURST(&Ks[1][0], scB0, scB1);
    __builtin_amdgcn_s_setprio(0);
    EXPPACK(scA0, scA1, pBA);
    STAGEWR(1);
    __syncthreads();
    vw = 2;
  }

  // STEP(t): loads; {QK(t)->SCN || PV(t-2) w/ PBO} MFMA burst;
  //          EXPPACK(SCP)->PBN; writes; barrier.
#define STEP(KT, SCN0, SCN1, SCP0, SCP1, PBN, PBO)                    \
  {                                                                   \
    LOADS(KT);                                                        \
    const int vr2 = (vw + 1 == 3) ? 0 : vw + 1; /* (t-2)%3 */         \
    __builtin_amdgcn_s_setprio(1);                                    \
    QKBURST(&Ks[(KT)&1][0], SCN0, SCN1);                              \
    PVBURST(&Vs[vr2][0], PBO);                                        \
    __builtin_amdgcn_s_setprio(0);                                    \
    EXPPACK(SCP0, SCP1, PBN);                                         \
    STAGEWR(KT);                                                      \
    __syncthreads();                                                  \
    vw = (vw == 2) ? 0 : vw + 1;                                      \
  }

  // ---- main loop: t = 2..NT-1 (even/odd pairs; NT-2 = 30 even) ----
  for (int kt = 2; kt < NT; kt += 2) {
    STEP(kt, scA0, scA1, scB0, scB1, pBB, pBA);       // even t
    STEP(kt + 1, scB0, scB1, scA0, scA1, pBA, pBB);   // odd t
  }

  // ---- epilogue ----
  // after loop: scB=sc(31), pBA=exp(sc(30)); PV done through t-2=29.
  // vw = 32%3 = 2. V(30) slot = (vw+1)%3 = 0; V(31) slot = (vw+2)%3 = 1.
  {
    __builtin_amdgcn_s_setprio(1);
    PVBURST(&Vs[0][0], pBA);  // PV(30)
    __builtin_amdgcn_s_setprio(0);
    EXPPACK(scB0, scB1, pBB);
    __builtin_amdgcn_s_setprio(1);
    PVBURST(&Vs[1][0], pBB);  // PV(31)
    __builtin_amdgcn_s_setprio(0);
  }
#undef STEP
#undef LOADS
#undef STAGEWR
#undef PVBURST
#undef QKBURST
#undef EXPPACK

  // lsum[0] = full column sum for this lane's q
  const float inv = 1.0f / lsum[0];
  const int b = bh >> 2, hh = bh & 3;
  short* ap = Abf + ((size_t)b * S + qrow + q31) * 256 + hh * 64;
#pragma unroll
  for (int dt = 0; dt < 2; ++dt) {
    const f32x16& o = dt ? o1 : o0;
#pragma unroll
    for (int g = 0; g < 4; ++g) {
      const int d0 = dt * 32 + 8 * g + 4 * h;
      bf16x4 r = pk4(o[4 * g + 0] * inv, o[4 * g + 1] * inv,
                     o[4 * g + 2] * inv, o[4 * g + 3] * inv);
      *(bf16x4*)(ap + d0) = r;
    }
  }
}

}  // namespace

extern "C" void kernel_launch(void* const* d_in, const int* in_sizes, int n_in,
                              void* d_out, int out_size, void* d_ws, size_t ws_size,
                              hipStream_t stream) {
  const float* x  = (const float*)d_in[0];
  const float* Wq = (const float*)d_in[1];
  const float* bq = (const float*)d_in[2];
  const float* Wk = (const float*)d_in[3];
  const float* bk = (const float*)d_in[4];
  const float* Wv = (const float*)d_in[5];
  const float* bv = (const float*)d_in[6];
  const float* Wo = (const float*)d_in[7];
  const float* bo = (const float*)d_in[8];
  float* out = (float*)d_out;

  const size_t per = (size_t)M * D;
  short* WqT = (short*)d_ws;
  short* WkT = WqT + 256 * 256;
  short* WvT = WkT + 256 * 256;
  short* WoT = WvT + 256 * 256;
  short* Qbf = WoT + 256 * 256;
  short* Kbf = Qbf + per;
  short* Vt  = Kbf + per;          // [bh][d][s]
  short* Abf = Vt + per;

  prep_w_kernel<<<64, 256, 0, stream>>>(Wq, Wk, Wv, Wo, WqT, WkT, WvT, WoT);
  gemm_qkv_kernel<<<dim3(256, 3), 256, 0, stream>>>(x, WqT, WkT, WvT, bq, bk, bv,
                                                    Qbf, Kbf, Vt);
  attn_kernel15<<<512, 256, 0, stream>>>(Qbf, Kbf, Vt, Abf);
  gemm_out_kernel<<<256, 256, 0, stream>>>(Abf, WoT, bo, out);
}